// Round 2
// baseline (3874.966 us; speedup 1.0000x reference)
//
#include <hip/hip_runtime.h>
#include <hip/hip_bf16.h>

#define C 192
#define NHh 6
#define KDd 32
#define QKVo 576
#define QS 580   // qkv LDS row stride (bf16): byte stride 1160 % 8 == 0 (b64-aligned)
#define XS 196   // xn  LDS row stride (bf16): byte stride 392  % 8 == 0
#define NT 49
#define IMG 64
#define WSZ 7

__device__ __forceinline__ float bf2f(unsigned short u) {
    union { unsigned int i; float f; } v; v.i = ((unsigned int)u) << 16; return v.f;
}
__device__ __forceinline__ unsigned short f2bf(float f) {
    __hip_bfloat16 h = __float2bfloat16(f);
    return *(unsigned short*)&h;
}

// ---------------- K1: windowed attention block -> x2 = x + attn_out (bf16 scratch) ----------------
__global__ __launch_bounds__(256) void attn_win_kernel(
    const float* __restrict__ x,
    const float* __restrict__ ln1_w, const float* __restrict__ ln1_b,
    const float* __restrict__ qkv_w, const float* __restrict__ qkv_b,
    const float* __restrict__ biases, int noff,
    const int* __restrict__ bidx,
    const float* __restrict__ proj_w, const float* __restrict__ proj_b,
    unsigned short* __restrict__ x2)
{
    extern __shared__ char smem[];
    unsigned short* qkv = (unsigned short*)smem;               // [NT][QS]
    unsigned short* xn  = (unsigned short*)(smem + NT*QS*2);   // [NT][XS]
    float* stats = (float*)(smem + NT*QS*2 + NT*XS*2);         // [NT][2]

    const int tid = threadIdx.x;
    const int blk = blockIdx.x;
    const int b  = blk / 100;
    const int wi = (blk / 10) % 10;
    const int wj = blk % 10;
    const size_t base = (size_t)b * 4096;

    // P0: load window tokens (zeros for padded positions), f32 -> bf16 LDS
    for (int idx = tid; idx < NT*(C/4); idx += 256) {
        int t = idx / (C/4), c0 = (idx - t*(C/4)) * 4;
        int gh = wi*WSZ + t/WSZ, gw = wj*WSZ + t%WSZ;
        ushort4 sv; sv.x = 0; sv.y = 0; sv.z = 0; sv.w = 0;
        if (gh < IMG && gw < IMG) {
            float4 v = *(const float4*)(x + (base + (size_t)(gh*IMG + gw))*C + c0);
            sv.x = f2bf(v.x); sv.y = f2bf(v.y); sv.z = f2bf(v.z); sv.w = f2bf(v.w);
        }
        *(ushort4*)&xn[t*XS + c0] = sv;
    }
    __syncthreads();

    // P1: LN1 stats (one thread per token)
    if (tid < NT) {
        float s = 0.f, s2 = 0.f;
        for (int c = 0; c < C; ++c) { float v = bf2f(xn[tid*XS + c]); s += v; s2 += v*v; }
        float m = s * (1.f/C);
        float var = s2 * (1.f/C) - m*m;
        stats[2*tid]   = m;
        stats[2*tid+1] = rsqrtf(var + 1e-5f);
    }
    __syncthreads();

    // P2: normalize in place
    for (int idx = tid; idx < NT*C; idx += 256) {
        int t = idx / C, c = idx - t*C;
        float v = bf2f(xn[t*XS + c]);
        v = (v - stats[2*t]) * stats[2*t+1] * ln1_w[c] + ln1_b[c];
        xn[t*XS + c] = f2bf(v);
    }
    __syncthreads();

    // P3: qkv GEMM (49x576), 4 outputs/thread-iter, f32 weights
    for (int idx = tid; idx < NT*(QKVo/4); idx += 256) {
        int t  = idx / (QKVo/4);
        int o0 = (idx - t*(QKVo/4)) * 4;
        float4 bv = *(const float4*)(qkv_b + o0);
        float a0 = bv.x, a1 = bv.y, a2 = bv.z, a3 = bv.w;
        const float4* wp4 = (const float4*)(qkv_w + o0);
        const unsigned short* xr = xn + t*XS;
        for (int c = 0; c < C; ++c) {
            float xv = bf2f(xr[c]);
            float4 wv = wp4[(size_t)c * (QKVo/4)];
            a0 += xv * wv.x;
            a1 += xv * wv.y;
            a2 += xv * wv.z;
            a3 += xv * wv.w;
        }
        int off = t*QS + o0;
        ushort4 qv; qv.x = f2bf(a0); qv.y = f2bf(a1); qv.z = f2bf(a2); qv.w = f2bf(a3);
        *(ushort4*)&qkv[off] = qv;
    }
    __syncthreads();

    // P4: per-(head,row) attention, online softmax, result into xn[q][h*32+d]
    for (int r = tid; r < NHh*NT; r += 256) {
        int h = r / NT, q = r - h*NT;
        const unsigned short* qrow = qkv + q*QS + h*96;
        float qv[KDd];
        #pragma unroll
        for (int d = 0; d < KDd; ++d) qv[d] = bf2f(qrow[d]);
        float m = -3.0e38f, l = 0.f;
        float acc[KDd];
        #pragma unroll
        for (int d = 0; d < KDd; ++d) acc[d] = 0.f;
        const int* brow = bidx + q*NT;
        #pragma unroll 1
        for (int k = 0; k < NT; ++k) {
            const unsigned short* krow = qkv + k*QS + h*96 + 32;
            float s = 0.f;
            #pragma unroll
            for (int d = 0; d < KDd; ++d) s += qv[d] * bf2f(krow[d]);
            s = s * 0.17677669529663687f + biases[h*noff + brow[k]];
            float nm   = fmaxf(m, s);
            float corr = __expf(m - nm);
            float p    = __expf(s - nm);
            l = l * corr + p;
            const unsigned short* vrow = qkv + k*QS + h*96 + 64;
            #pragma unroll
            for (int d = 0; d < KDd; ++d) acc[d] = acc[d]*corr + p * bf2f(vrow[d]);
            m = nm;
        }
        float inv = 1.f / l;
        unsigned short* orow = xn + q*XS + h*KDd;
        #pragma unroll
        for (int d = 0; d < KDd; ++d) orow[d] = f2bf(acc[d]*inv);
    }
    __syncthreads();

    // P5: proj(192x192) + bias + shortcut, write x2 (bf16, valid tokens only)
    for (int idx = tid; idx < NT*(C/4); idx += 256) {
        int t  = idx / (C/4);
        int c0 = (idx - t*(C/4)) * 4;
        int gh = wi*WSZ + t/WSZ, gw = wj*WSZ + t%WSZ;
        if (gh >= IMG || gw >= IMG) continue;
        float4 bv = *(const float4*)(proj_b + c0);
        float a0 = bv.x, a1 = bv.y, a2 = bv.z, a3 = bv.w;
        const float4* wp4 = (const float4*)(proj_w + c0);
        const unsigned short* ar = xn + t*XS;
        for (int j = 0; j < C; ++j) {
            float xv = bf2f(ar[j]);
            float4 wv = wp4[(size_t)j * (C/4)];
            a0 += xv * wv.x;
            a1 += xv * wv.y;
            a2 += xv * wv.z;
            a3 += xv * wv.w;
        }
        size_t g = (base + (size_t)(gh*IMG + gw)) * C + c0;
        float4 xin = *(const float4*)(x + g);
        a0 += xin.x; a1 += xin.y; a2 += xin.z; a3 += xin.w;
        ushort4 ov;
        ov.x = f2bf(a0); ov.y = f2bf(a1); ov.z = f2bf(a2); ov.w = f2bf(a3);
        *(ushort4*)(x2 + g) = ov;
    }
}

// -------- K2: depthwise conv3x3 + BN (-> x3) + LN2 + MLP + residual -> out (f32) --------
__global__ __launch_bounds__(256) void conv_mlp_kernel(
    const unsigned short* __restrict__ x2,
    const float* __restrict__ conv_w,
    const float* __restrict__ bn_g, const float* __restrict__ bn_b,
    const float* __restrict__ bn_m, const float* __restrict__ bn_v,
    const float* __restrict__ ln2_w, const float* __restrict__ ln2_b,
    const float* __restrict__ fc1_w, const float* __restrict__ fc1_b,
    const float* __restrict__ fc2_w, const float* __restrict__ fc2_b,
    float* __restrict__ out)
{
    __shared__ float x3[16][C+1];
    __shared__ float xnl[16][C+1];
    __shared__ unsigned short h1[16][768];
    __shared__ float stats[16][2];

    const int tid  = threadIdx.x;
    const int base = blockIdx.x * 16;     // global token index of first token
    const int b    = base >> 12;
    const int n0   = base & 4095;
    const size_t ibase = (size_t)b * 4096;

    // P0: depthwise conv 3x3 (from bf16 x2) + BN affine -> x3 (fp32 LDS)
    for (int idx = tid; idx < 16*C; idx += 256) {
        int lt = idx / C, c = idx - lt*C;
        int n = n0 + lt, hh = n >> 6, ww = n & 63;
        float acc = 0.f;
        #pragma unroll
        for (int kh = -1; kh <= 1; ++kh) {
            int h2 = hh + kh;
            if (h2 < 0 || h2 >= IMG) continue;
            #pragma unroll
            for (int kw = -1; kw <= 1; ++kw) {
                int w2 = ww + kw;
                if (w2 < 0 || w2 >= IMG) continue;
                acc += bf2f(x2[(ibase + (size_t)(h2*IMG + w2))*C + c]) *
                       conv_w[c*9 + (kh+1)*3 + (kw+1)];
            }
        }
        float scale = bn_g[c] * rsqrtf(bn_v[c] + 1e-5f);
        x3[lt][c] = acc * scale + (bn_b[c] - bn_m[c] * scale);
    }
    __syncthreads();

    // P1: LN2 stats
    if (tid < 16) {
        float s = 0.f, s2 = 0.f;
        for (int c = 0; c < C; ++c) { float v = x3[tid][c]; s += v; s2 += v*v; }
        float m = s * (1.f/C), var = s2 * (1.f/C) - m*m;
        stats[tid][0] = m;
        stats[tid][1] = rsqrtf(var + 1e-5f);
    }
    __syncthreads();

    // P2: normalize
    for (int idx = tid; idx < 16*C; idx += 256) {
        int lt = idx / C, c = idx - lt*C;
        xnl[lt][c] = (x3[lt][c] - stats[lt][0]) * stats[lt][1] * ln2_w[c] + ln2_b[c];
    }
    __syncthreads();

    // P3: fc1 (192->768) + exact GELU -> h1 (bf16 LDS)
    for (int idx = tid; idx < 16*(768/4); idx += 256) {
        int lt = idx / 192, o0 = (idx - lt*192) * 4;
        float4 bv = *(const float4*)(fc1_b + o0);
        float a0 = bv.x, a1 = bv.y, a2 = bv.z, a3 = bv.w;
        const float4* wp4 = (const float4*)(fc1_w + o0);
        for (int c = 0; c < C; ++c) {
            float xv = xnl[lt][c];
            float4 wv = wp4[(size_t)c * 192];
            a0 += xv * wv.x;
            a1 += xv * wv.y;
            a2 += xv * wv.z;
            a3 += xv * wv.w;
        }
        a0 = 0.5f * a0 * (1.f + erff(a0 * 0.70710678118f));
        a1 = 0.5f * a1 * (1.f + erff(a1 * 0.70710678118f));
        a2 = 0.5f * a2 * (1.f + erff(a2 * 0.70710678118f));
        a3 = 0.5f * a3 * (1.f + erff(a3 * 0.70710678118f));
        ushort4 hv; hv.x = f2bf(a0); hv.y = f2bf(a1); hv.z = f2bf(a2); hv.w = f2bf(a3);
        *(ushort4*)&h1[lt][o0] = hv;
    }
    __syncthreads();

    // P4: fc2 (768->192) + bias + residual(x3) -> out (f32)
    for (int idx = tid; idx < 16*(C/4); idx += 256) {
        int lt = idx / (C/4), c0 = (idx - lt*(C/4)) * 4;
        float4 bv = *(const float4*)(fc2_b + c0);
        float a0 = bv.x, a1 = bv.y, a2 = bv.z, a3 = bv.w;
        const float4* wp4 = (const float4*)(fc2_w + c0);
        for (int j = 0; j < 768; ++j) {
            float hv = bf2f(h1[lt][j]);
            float4 wv = wp4[(size_t)j * (C/4)];
            a0 += hv * wv.x;
            a1 += hv * wv.y;
            a2 += hv * wv.z;
            a3 += hv * wv.w;
        }
        a0 += x3[lt][c0+0];
        a1 += x3[lt][c0+1];
        a2 += x3[lt][c0+2];
        a3 += x3[lt][c0+3];
        size_t g = ((size_t)base + lt) * C + c0;
        float4 ov; ov.x = a0; ov.y = a1; ov.z = a2; ov.w = a3;
        *(float4*)(out + g) = ov;
    }
}

extern "C" void kernel_launch(void* const* d_in, const int* in_sizes, int n_in,
                              void* d_out, int out_size, void* d_ws, size_t ws_size,
                              hipStream_t stream)
{
    const float* x      = (const float*)d_in[0];
    const float* ln1_w  = (const float*)d_in[1];
    const float* ln1_b  = (const float*)d_in[2];
    const float* qkv_w  = (const float*)d_in[3];
    const float* qkv_b  = (const float*)d_in[4];
    const float* biases = (const float*)d_in[5];
    const float* proj_w = (const float*)d_in[6];
    const float* proj_b = (const float*)d_in[7];
    const float* conv_w = (const float*)d_in[8];
    const float* bn_g   = (const float*)d_in[9];
    const float* bn_b   = (const float*)d_in[10];
    const float* bn_m   = (const float*)d_in[11];
    const float* bn_v   = (const float*)d_in[12];
    const float* ln2_w  = (const float*)d_in[13];
    const float* ln2_b  = (const float*)d_in[14];
    const float* fc1_w  = (const float*)d_in[15];
    const float* fc1_b  = (const float*)d_in[16];
    const float* fc2_w  = (const float*)d_in[17];
    const float* fc2_b  = (const float*)d_in[18];
    const int* bidx     = (const int*)d_in[19];

    unsigned short* x2 = (unsigned short*)d_ws;   // 16*4096*192 bf16 = 25.2 MB scratch
    float* out = (float*)d_out;
    int noff = in_sizes[5] / NHh;

    size_t smem1 = (size_t)NT*QS*2 + (size_t)NT*XS*2 + (size_t)NT*2*4;  // 76,440 B
    hipFuncSetAttribute((const void*)attn_win_kernel,
                        hipFuncAttributeMaxDynamicSharedMemorySize, (int)smem1);

    attn_win_kernel<<<16*100, 256, smem1, stream>>>(
        x, ln1_w, ln1_b, qkv_w, qkv_b, biases, noff, bidx, proj_w, proj_b, x2);

    conv_mlp_kernel<<<(16*4096)/16, 256, 0, stream>>>(
        x2, conv_w, bn_g, bn_b, bn_m, bn_v, ln2_w, ln2_b,
        fc1_w, fc1_b, fc2_w, fc2_b, out);
}

// Round 4
// 2076.816 us; speedup vs baseline: 1.8658x; 1.8658x over previous
//
#include <hip/hip_runtime.h>
#include <hip/hip_bf16.h>

#define C 192
#define NHh 6
#define KDd 32
#define QKVo 576
#define QS 580   // qkv LDS row stride (bf16): byte stride 1160 % 8 == 0
#define XS 196   // xn  LDS row stride (bf16): byte stride 392  % 8 == 0
#define NT 49
#define IMG 64
#define WSZ 7

typedef __attribute__((ext_vector_type(8))) short bf16x8;
typedef __attribute__((ext_vector_type(4))) float f32x4;

__device__ __forceinline__ float bf2f(unsigned short u) {
    union { unsigned int i; float f; } v; v.i = ((unsigned int)u) << 16; return v.f;
}
__device__ __forceinline__ unsigned short f2bf(float f) {
    __hip_bfloat16 h = __float2bfloat16(f);
    return *(unsigned short*)&h;
}
__device__ __forceinline__ float gelu_f(float v) {
    return 0.5f * v * (1.f + erff(v * 0.70710678118654752f));
}

// ---------------- P: prep — transpose weights to bf16, expand bias table ----------------
__global__ __launch_bounds__(256) void prep_kernel(
    const float* __restrict__ fc1_w, const float* __restrict__ fc2_w,
    const float* __restrict__ biases, int noff, const int* __restrict__ bidx,
    unsigned short* __restrict__ wfc1t, unsigned short* __restrict__ wfc2t,
    float* __restrict__ biasf)
{
    int i = blockIdx.x * 256 + threadIdx.x;
    if (i < 147456) {                       // wfc1t[n][k] = fc1_w[k][n], 768x192
        int n = i / 192, k = i - n * 192;
        wfc1t[i] = f2bf(fc1_w[k * 768 + n]);
    } else if (i < 294912) {                // wfc2t[n][k] = fc2_w[k][n], 192x768
        int j = i - 147456;
        int n = j / 768, k = j - n * 768;
        wfc2t[j] = f2bf(fc2_w[k * 192 + n]);
    } else if (i < 294912 + NHh * NT * NT) { // biasf[h][q][k]
        int j = i - 294912;
        int h = j / (NT * NT), qk = j - h * (NT * NT);
        biasf[j] = biases[h * noff + bidx[qk]];
    }
}

// ---------------- K1: windowed attention block -> x2 = x + attn_out (bf16 scratch) ----------------
__global__ __launch_bounds__(256) void attn_win_kernel(
    const float* __restrict__ x,
    const float* __restrict__ ln1_w, const float* __restrict__ ln1_b,
    const float* __restrict__ qkv_w, const float* __restrict__ qkv_b,
    const float* __restrict__ biasf,
    const float* __restrict__ proj_w, const float* __restrict__ proj_b,
    unsigned short* __restrict__ x2)
{
    extern __shared__ char smem[];
    unsigned short* qkv = (unsigned short*)smem;               // [NT][QS]
    unsigned short* xn  = (unsigned short*)(smem + NT*QS*2);   // [NT][XS]
    float* stats = (float*)(smem + NT*QS*2 + NT*XS*2);         // [NT][2]

    const int tid = threadIdx.x;
    const int blk = blockIdx.x;
    const int b  = blk / 100;
    const int wi = (blk / 10) % 10;
    const int wj = blk % 10;
    const size_t base = (size_t)b * 4096;

    // P0: load window tokens (zeros for padded positions), f32 -> bf16 LDS
    for (int idx = tid; idx < NT*(C/4); idx += 256) {
        int t = idx / (C/4), c0 = (idx - t*(C/4)) * 4;
        int gh = wi*WSZ + t/WSZ, gw = wj*WSZ + t%WSZ;
        ushort4 sv; sv.x = 0; sv.y = 0; sv.z = 0; sv.w = 0;
        if (gh < IMG && gw < IMG) {
            float4 v = *(const float4*)(x + (base + (size_t)(gh*IMG + gw))*C + c0);
            sv.x = f2bf(v.x); sv.y = f2bf(v.y); sv.z = f2bf(v.z); sv.w = f2bf(v.w);
        }
        *(ushort4*)&xn[t*XS + c0] = sv;
    }
    __syncthreads();

    // P1: LN1 stats (one thread per token)
    if (tid < NT) {
        float s = 0.f, s2 = 0.f;
        for (int c = 0; c < C; ++c) { float v = bf2f(xn[tid*XS + c]); s += v; s2 += v*v; }
        float m = s * (1.f/C);
        float var = s2 * (1.f/C) - m*m;
        stats[2*tid]   = m;
        stats[2*tid+1] = rsqrtf(var + 1e-5f);
    }
    __syncthreads();

    // P2: normalize in place
    for (int idx = tid; idx < NT*C; idx += 256) {
        int t = idx / C, c = idx - t*C;
        float v = bf2f(xn[t*XS + c]);
        v = (v - stats[2*t]) * stats[2*t+1] * ln1_w[c] + ln1_b[c];
        xn[t*XS + c] = f2bf(v);
    }
    __syncthreads();

    // P3: qkv GEMM (49x576), 4 outputs/thread-iter, f32 weights
    for (int idx = tid; idx < NT*(QKVo/4); idx += 256) {
        int t  = idx / (QKVo/4);
        int o0 = (idx - t*(QKVo/4)) * 4;
        float4 bv = *(const float4*)(qkv_b + o0);
        float a0 = bv.x, a1 = bv.y, a2 = bv.z, a3 = bv.w;
        const float4* wp4 = (const float4*)(qkv_w + o0);
        const unsigned short* xr = xn + t*XS;
        for (int c = 0; c < C; ++c) {
            float xv = bf2f(xr[c]);
            float4 wv = wp4[(size_t)c * (QKVo/4)];
            a0 += xv * wv.x;
            a1 += xv * wv.y;
            a2 += xv * wv.z;
            a3 += xv * wv.w;
        }
        int off = t*QS + o0;
        ushort4 qv; qv.x = f2bf(a0); qv.y = f2bf(a1); qv.z = f2bf(a2); qv.w = f2bf(a3);
        *(ushort4*)&qkv[off] = qv;
    }
    __syncthreads();

    // P4: per-(head,row) attention, online softmax, result into xn[q][h*32+d]
    for (int r = tid; r < NHh*NT; r += 256) {
        int h = r / NT, q = r - h*NT;
        const unsigned short* qrow = qkv + q*QS + h*96;
        float qv[KDd];
        #pragma unroll
        for (int d = 0; d < KDd; ++d) qv[d] = bf2f(qrow[d]);
        float m = -3.0e38f, l = 0.f;
        float acc[KDd];
        #pragma unroll
        for (int d = 0; d < KDd; ++d) acc[d] = 0.f;
        const float* brow = biasf + (h*NT + q)*NT;
        #pragma unroll 1
        for (int k = 0; k < NT; ++k) {
            const unsigned short* krow = qkv + k*QS + h*96 + 32;
            float s = 0.f;
            #pragma unroll
            for (int d = 0; d < KDd; ++d) s += qv[d] * bf2f(krow[d]);
            s = s * 0.17677669529663687f + brow[k];
            float nm   = fmaxf(m, s);
            float corr = __expf(m - nm);
            float p    = __expf(s - nm);
            l = l * corr + p;
            const unsigned short* vrow = qkv + k*QS + h*96 + 64;
            #pragma unroll
            for (int d = 0; d < KDd; ++d) acc[d] = acc[d]*corr + p * bf2f(vrow[d]);
            m = nm;
        }
        float inv = 1.f / l;
        unsigned short* orow = xn + q*XS + h*KDd;
        #pragma unroll
        for (int d = 0; d < KDd; ++d) orow[d] = f2bf(acc[d]*inv);
    }
    __syncthreads();

    // P5: proj(192x192) + bias + shortcut, write x2 (bf16, valid tokens only)
    for (int idx = tid; idx < NT*(C/4); idx += 256) {
        int t  = idx / (C/4);
        int c0 = (idx - t*(C/4)) * 4;
        int gh = wi*WSZ + t/WSZ, gw = wj*WSZ + t%WSZ;
        if (gh >= IMG || gw >= IMG) continue;
        float4 bv = *(const float4*)(proj_b + c0);
        float a0 = bv.x, a1 = bv.y, a2 = bv.z, a3 = bv.w;
        const float4* wp4 = (const float4*)(proj_w + c0);
        const unsigned short* ar = xn + t*XS;
        for (int j = 0; j < C; ++j) {
            float xv = bf2f(ar[j]);
            float4 wv = wp4[(size_t)j * (C/4)];
            a0 += xv * wv.x;
            a1 += xv * wv.y;
            a2 += xv * wv.z;
            a3 += xv * wv.w;
        }
        size_t g = (base + (size_t)(gh*IMG + gw)) * C + c0;
        float4 xin = *(const float4*)(x + g);
        a0 += xin.x; a1 += xin.y; a2 += xin.z; a3 += xin.w;
        ushort4 ov;
        ov.x = f2bf(a0); ov.y = f2bf(a1); ov.z = f2bf(a2); ov.w = f2bf(a3);
        *(ushort4*)(x2 + g) = ov;
    }
}

// -------- K2 (MFMA): conv3x3+BN -> x3 ; LN2 ; fc1+GELU ; fc2 + residual -> out --------
// 32 tokens/block, 4 waves. LDS: x3[32][200] bf16, xn[32][200] bf16, h1[32][776] bf16, stats.
#define X3S 200
#define H1S 776
__global__ __launch_bounds__(256) void conv_mlp_mfma(
    const unsigned short* __restrict__ x2,
    const float* __restrict__ conv_w,
    const float* __restrict__ bn_g, const float* __restrict__ bn_b,
    const float* __restrict__ bn_m, const float* __restrict__ bn_v,
    const float* __restrict__ ln2_w, const float* __restrict__ ln2_b,
    const unsigned short* __restrict__ wfc1t, const float* __restrict__ fc1_b,
    const unsigned short* __restrict__ wfc2t, const float* __restrict__ fc2_b,
    float* __restrict__ out)
{
    extern __shared__ char smem[];
    unsigned short* x3 = (unsigned short*)smem;             // [32][X3S]
    unsigned short* xn = (unsigned short*)(smem + 12800);   // [32][X3S]
    unsigned short* h1 = (unsigned short*)(smem + 25600);   // [32][H1S]
    float* stats = (float*)(smem + 75264);                  // [32][2]

    const int tid  = threadIdx.x;
    const int base = blockIdx.x * 32;
    const int b    = base >> 12;
    const int n0   = base & 4095;
    const int hh   = n0 >> 6;
    const int w0v  = n0 & 63;
    const size_t ibase = (size_t)b * 4096;

    // P0: depthwise conv 3x3 + BN -> x3 (bf16)
    for (int idx = tid; idx < 32*C; idx += 256) {
        int lt = idx / C, c = idx - lt*C;
        int ww = w0v + lt;
        float acc = 0.f;
        #pragma unroll
        for (int kh = -1; kh <= 1; ++kh) {
            int h2 = hh + kh;
            if (h2 < 0 || h2 >= IMG) continue;
            #pragma unroll
            for (int kw = -1; kw <= 1; ++kw) {
                int w2 = ww + kw;
                if (w2 < 0 || w2 >= IMG) continue;
                acc += bf2f(x2[(ibase + (size_t)(h2*IMG + w2))*C + c]) *
                       conv_w[c*9 + (kh+1)*3 + (kw+1)];
            }
        }
        float scale = bn_g[c] * rsqrtf(bn_v[c] + 1e-5f);
        x3[lt*X3S + c] = f2bf(acc * scale + (bn_b[c] - bn_m[c] * scale));
    }
    __syncthreads();

    // P1: LN2 stats — 8 lanes per token, shuffle reduce
    {
        int lt = tid >> 3, sl = tid & 7;
        float s = 0.f, s2 = 0.f;
        for (int c = sl; c < C; c += 8) {
            float v = bf2f(x3[lt*X3S + c]);
            s += v; s2 += v*v;
        }
        #pragma unroll
        for (int msk = 1; msk < 8; msk <<= 1) {
            s  += __shfl_xor(s,  msk, 64);
            s2 += __shfl_xor(s2, msk, 64);
        }
        if (sl == 0) {
            float m = s * (1.f/C), var = s2 * (1.f/C) - m*m;
            stats[2*lt]   = m;
            stats[2*lt+1] = rsqrtf(var + 1e-5f);
        }
    }
    __syncthreads();

    // P2: normalize -> xn (bf16)
    for (int idx = tid; idx < 32*C; idx += 256) {
        int lt = idx / C, c = idx - lt*C;
        float v = bf2f(x3[lt*X3S + c]);
        xn[lt*X3S + c] = f2bf((v - stats[2*lt]) * stats[2*lt+1] * ln2_w[c] + ln2_b[c]);
    }
    __syncthreads();

    // P3: fc1 (32x768 = xn(32x192) @ W1) + GELU -> h1. Per wave: N-range 192, 12 n-tiles.
    const int wid = tid >> 6, l = tid & 63, lr = l & 15, lk = l >> 4;
    {
        const int nbase = wid * 192;
        for (int nt = 0; nt < 12; ++nt) {
            const int ncol = nbase + nt*16 + lr;
            f32x4 a0 = {0.f,0.f,0.f,0.f}, a1 = {0.f,0.f,0.f,0.f};
            const unsigned short* wp  = wfc1t + ncol*C + lk*8;
            const unsigned short* xp0 = xn + lr*X3S + lk*8;
            const unsigned short* xp1 = xn + (16+lr)*X3S + lk*8;
            #pragma unroll
            for (int ks = 0; ks < 6; ++ks) {
                bf16x8 bfr = *(const bf16x8*)(wp  + ks*32);
                bf16x8 af0 = *(const bf16x8*)(xp0 + ks*32);
                bf16x8 af1 = *(const bf16x8*)(xp1 + ks*32);
                a0 = __builtin_amdgcn_mfma_f32_16x16x32_bf16(af0, bfr, a0, 0, 0, 0);
                a1 = __builtin_amdgcn_mfma_f32_16x16x32_bf16(af1, bfr, a1, 0, 0, 0);
            }
            float bias = fc1_b[ncol];
            #pragma unroll
            for (int r = 0; r < 4; ++r) {
                int row0 = lk*4 + r;
                h1[row0*H1S + ncol]      = f2bf(gelu_f(a0[r] + bias));
                h1[(row0+16)*H1S + ncol] = f2bf(gelu_f(a1[r] + bias));
            }
        }
    }
    __syncthreads();

    // P4: fc2 (32x192 = h1(32x768) @ W2) + bias + residual(x3) -> out. Per wave: N-range 48.
    {
        const int nb2 = wid * 48;
        f32x4 acc0[3] = {{0.f,0.f,0.f,0.f},{0.f,0.f,0.f,0.f},{0.f,0.f,0.f,0.f}};
        f32x4 acc1[3] = {{0.f,0.f,0.f,0.f},{0.f,0.f,0.f,0.f},{0.f,0.f,0.f,0.f}};
        const unsigned short* hp0 = h1 + lr*H1S + lk*8;
        const unsigned short* hp1 = h1 + (16+lr)*H1S + lk*8;
        const unsigned short* wp0 = wfc2t + (nb2 + 0*16 + lr)*768 + lk*8;
        const unsigned short* wp1 = wfc2t + (nb2 + 1*16 + lr)*768 + lk*8;
        const unsigned short* wp2 = wfc2t + (nb2 + 2*16 + lr)*768 + lk*8;
        #pragma unroll 4
        for (int ks = 0; ks < 24; ++ks) {
            bf16x8 af0 = *(const bf16x8*)(hp0 + ks*32);
            bf16x8 af1 = *(const bf16x8*)(hp1 + ks*32);
            bf16x8 b0  = *(const bf16x8*)(wp0 + ks*32);
            bf16x8 b1  = *(const bf16x8*)(wp1 + ks*32);
            bf16x8 b2  = *(const bf16x8*)(wp2 + ks*32);
            acc0[0] = __builtin_amdgcn_mfma_f32_16x16x32_bf16(af0, b0, acc0[0], 0, 0, 0);
            acc1[0] = __builtin_amdgcn_mfma_f32_16x16x32_bf16(af1, b0, acc1[0], 0, 0, 0);
            acc0[1] = __builtin_amdgcn_mfma_f32_16x16x32_bf16(af0, b1, acc0[1], 0, 0, 0);
            acc1[1] = __builtin_amdgcn_mfma_f32_16x16x32_bf16(af1, b1, acc1[1], 0, 0, 0);
            acc0[2] = __builtin_amdgcn_mfma_f32_16x16x32_bf16(af0, b2, acc0[2], 0, 0, 0);
            acc1[2] = __builtin_amdgcn_mfma_f32_16x16x32_bf16(af1, b2, acc1[2], 0, 0, 0);
        }
        #pragma unroll
        for (int n = 0; n < 3; ++n) {
            int col = nb2 + n*16 + lr;
            float bias = fc2_b[col];
            #pragma unroll
            for (int r = 0; r < 4; ++r) {
                int row0 = lk*4 + r;
                float v0 = acc0[n][r] + bias + bf2f(x3[row0*X3S + col]);
                float v1 = acc1[n][r] + bias + bf2f(x3[(row0+16)*X3S + col]);
                out[(size_t)(base + row0) * C + col]      = v0;
                out[(size_t)(base + row0 + 16) * C + col] = v1;
            }
        }
    }
}

extern "C" void kernel_launch(void* const* d_in, const int* in_sizes, int n_in,
                              void* d_out, int out_size, void* d_ws, size_t ws_size,
                              hipStream_t stream)
{
    const float* x      = (const float*)d_in[0];
    const float* ln1_w  = (const float*)d_in[1];
    const float* ln1_b  = (const float*)d_in[2];
    const float* qkv_w  = (const float*)d_in[3];
    const float* qkv_b  = (const float*)d_in[4];
    const float* biases = (const float*)d_in[5];
    const float* proj_w = (const float*)d_in[6];
    const float* proj_b = (const float*)d_in[7];
    const float* conv_w = (const float*)d_in[8];
    const float* bn_g   = (const float*)d_in[9];
    const float* bn_b   = (const float*)d_in[10];
    const float* bn_m   = (const float*)d_in[11];
    const float* bn_v   = (const float*)d_in[12];
    const float* ln2_w  = (const float*)d_in[13];
    const float* ln2_b  = (const float*)d_in[14];
    const float* fc1_w  = (const float*)d_in[15];
    const float* fc1_b  = (const float*)d_in[16];
    const float* fc2_w  = (const float*)d_in[17];
    const float* fc2_b  = (const float*)d_in[18];
    const int* bidx     = (const int*)d_in[19];

    char* ws = (char*)d_ws;
    unsigned short* x2    = (unsigned short*)ws;                 // 25,165,824 B
    unsigned short* wfc1t = (unsigned short*)(ws + 25165824);    // 294,912 B
    unsigned short* wfc2t = (unsigned short*)(ws + 25165824 + 294912);
    float*          biasf = (float*)(ws + 25165824 + 2*294912); // 57,624 B
    float* out = (float*)d_out;
    int noff = in_sizes[5] / NHh;

    prep_kernel<<<(294912 + NHh*NT*NT + 255)/256, 256, 0, stream>>>(
        fc1_w, fc2_w, biases, noff, bidx, wfc1t, wfc2t, biasf);

    size_t smem1 = (size_t)NT*QS*2 + (size_t)NT*XS*2 + (size_t)NT*2*4;  // 76,440 B
    hipFuncSetAttribute((const void*)attn_win_kernel,
                        hipFuncAttributeMaxDynamicSharedMemorySize, (int)smem1);
    attn_win_kernel<<<16*100, 256, smem1, stream>>>(
        x, ln1_w, ln1_b, qkv_w, qkv_b, biasf, proj_w, proj_b, x2);

    size_t smem2 = 75520;
    hipFuncSetAttribute((const void*)conv_mlp_mfma,
                        hipFuncAttributeMaxDynamicSharedMemorySize, (int)smem2);
    conv_mlp_mfma<<<65536/32, 256, smem2, stream>>>(
        x2, conv_w, bn_g, bn_b, bn_m, bn_v, ln2_w, ln2_b,
        wfc1t, fc1_b, wfc2t, fc2_b, out);
}

// Round 6
// 761.772 us; speedup vs baseline: 5.0868x; 2.7263x over previous
//
#include <hip/hip_runtime.h>
#include <hip/hip_bf16.h>

#define C 192
#define NHh 6
#define NT 49
#define IMG 64
#define WSZ 7

#define XS2 200   // xn/ao LDS stride (bf16): 400B, 16B-aligned rows, 100 words = 4 mod 32
#define QKS 392   // qk stride: 784B rows, 196 words = 4 mod 32
#define VTS 72    // vt stride: 144B rows, 36 words = 4 mod 32
#define PLS 72    // p_lds stride

typedef __attribute__((ext_vector_type(8))) short bf16x8;
typedef __attribute__((ext_vector_type(4))) float f32x4;

__device__ __forceinline__ float bf2f(unsigned short u) {
    union { unsigned int i; float f; } v; v.i = ((unsigned int)u) << 16; return v.f;
}
__device__ __forceinline__ unsigned short f2bf(float f) {
    __hip_bfloat16 h = __float2bfloat16(f);
    return *(unsigned short*)&h;
}
__device__ __forceinline__ float gelu_f(float v) {
    return 0.5f * v * (1.f + erff(v * 0.70710678118654752f));
}

// ---------------- prep: bf16-transpose weights, padded bias table ----------------
__global__ __launch_bounds__(256) void prep_kernel(
    const float* __restrict__ fc1_w, const float* __restrict__ fc2_w,
    const float* __restrict__ qkv_w, const float* __restrict__ proj_w,
    const float* __restrict__ biases, int noff, const int* __restrict__ bidx,
    unsigned short* __restrict__ wfc1t, unsigned short* __restrict__ wfc2t,
    unsigned short* __restrict__ wqkvt, unsigned short* __restrict__ wprojt,
    float* __restrict__ biasfp)
{
    int i = blockIdx.x * 256 + threadIdx.x;
    if (i < 147456) {                        // wfc1t[n][k] = fc1_w[k][n], 768x192
        int n = i / 192, k = i - n * 192;
        wfc1t[i] = f2bf(fc1_w[k * 768 + n]);
    } else if (i < 294912) {                 // wfc2t[n][k] = fc2_w[k][n], 192x768
        int j = i - 147456;
        int n = j / 768, k = j - n * 768;
        wfc2t[j] = f2bf(fc2_w[k * 192 + n]);
    } else if (i < 405504) {                 // wqkvt[n][k] = qkv_w[k][n], 576x192
        int j = i - 294912;
        int n = j / 192, k = j - n * 192;
        wqkvt[j] = f2bf(qkv_w[k * 576 + n]);
    } else if (i < 442368) {                 // wprojt[n][k] = proj_w[k][n], 192x192
        int j = i - 405504;
        int n = j / 192, k = j - n * 192;
        wprojt[j] = f2bf(proj_w[k * 192 + n]);
    } else if (i < 442368 + NHh * 64 * 64) { // biasfp[h][q64][k64], -1e30 pad
        int j = i - 442368;
        int h = j >> 12, rem = j & 4095;
        int q = rem >> 6, k = rem & 63;
        biasfp[j] = (q < NT && k < NT) ? biases[h * noff + bidx[q * NT + k]] : -1.0e30f;
    }
}

// ---------------- K1 (MFMA): LN1 -> qkv -> windowed attention -> proj + residual ----------------
__global__ __launch_bounds__(256) void attn_win_mfma(
    const float* __restrict__ x,
    const float* __restrict__ ln1_w, const float* __restrict__ ln1_b,
    const unsigned short* __restrict__ wqkvt, const float* __restrict__ qkv_b,
    const float* __restrict__ biasfp,
    const unsigned short* __restrict__ wprojt, const float* __restrict__ proj_b,
    unsigned short* __restrict__ x2)
{
    extern __shared__ char smem[];
    unsigned short* xn = (unsigned short*)smem;               // [64][XS2]  25600 B (later reused as ao)
    unsigned short* qk = (unsigned short*)(smem + 25600);     // [64][QKS]  50176 B (q:0..31,k:32..63 per head)
    unsigned short* vt = (unsigned short*)(smem + 75776);     // [6*32][VTS] 27648 B (V transposed)
    unsigned short* pl = (unsigned short*)(smem + 103424);    // [4][16][PLS] 9216 B (per-wave P)
    float* stats = (float*)(smem + 112640);                   // [64][2]

    const int tid = threadIdx.x;
    const int blk = blockIdx.x;
    const int b  = blk / 100;
    const int wi = (blk / 10) % 10;
    const int wj = blk % 10;
    const size_t base = (size_t)b * 4096;
    const int wid = tid >> 6, lane = tid & 63, lr = lane & 15, lg = lane >> 4;

    // P0: load window (f32 -> bf16), zero-pad tokens 49..63 and OOB
    for (int idx = tid; idx < 64*48; idx += 256) {
        int t = idx / 48, c0 = (idx - t*48) * 4;
        ushort4 sv; sv.x = 0; sv.y = 0; sv.z = 0; sv.w = 0;
        if (t < NT) {
            int gh = wi*WSZ + t/WSZ, gw = wj*WSZ + t%WSZ;
            if (gh < IMG && gw < IMG) {
                float4 v = *(const float4*)(x + (base + (size_t)(gh*IMG + gw))*C + c0);
                sv.x = f2bf(v.x); sv.y = f2bf(v.y); sv.z = f2bf(v.z); sv.w = f2bf(v.w);
            }
        }
        *(ushort4*)&xn[t*XS2 + c0] = sv;
    }
    __syncthreads();

    // P1: LN1 stats, 4 lanes/token
    {
        int lt = tid >> 2, sl = tid & 3;
        float s = 0.f, s2 = 0.f;
        for (int c = sl; c < C; c += 4) {
            float v = bf2f(xn[lt*XS2 + c]);
            s += v; s2 += v*v;
        }
        s  += __shfl_xor(s, 1, 64);  s  += __shfl_xor(s, 2, 64);
        s2 += __shfl_xor(s2, 1, 64); s2 += __shfl_xor(s2, 2, 64);
        if (sl == 0) {
            float m = s * (1.f/C), var = s2 * (1.f/C) - m*m;
            stats[2*lt]   = m;
            stats[2*lt+1] = rsqrtf(var + 1e-5f);
        }
    }
    __syncthreads();

    // P2: normalize in place (rows >= 49 become ln1_b: finite, masked later)
    for (int idx = tid; idx < 64*48; idx += 256) {
        int t = idx / 48, c0 = (idx - t*48) * 4;
        float mm = stats[2*t], rr = stats[2*t+1];
        ushort4 sv = *(ushort4*)&xn[t*XS2 + c0];
        sv.x = f2bf((bf2f(sv.x) - mm) * rr * ln1_w[c0+0] + ln1_b[c0+0]);
        sv.y = f2bf((bf2f(sv.y) - mm) * rr * ln1_w[c0+1] + ln1_b[c0+1]);
        sv.z = f2bf((bf2f(sv.z) - mm) * rr * ln1_w[c0+2] + ln1_b[c0+2]);
        sv.w = f2bf((bf2f(sv.w) - mm) * rr * ln1_w[c0+3] + ln1_b[c0+3]);
        *(ushort4*)&xn[t*XS2 + c0] = sv;
    }
    __syncthreads();

    // P3: qkv GEMM 64x576 = xn(64x192) @ qkv_w; scatter C to qk / vt(transposed)
    for (int nt = 0; nt < 9; ++nt) {
        const int ncol = (wid*9 + nt)*16 + lr;
        f32x4 acc0 = {0.f,0.f,0.f,0.f}, acc1 = {0.f,0.f,0.f,0.f};
        f32x4 acc2 = {0.f,0.f,0.f,0.f}, acc3 = {0.f,0.f,0.f,0.f};
        const unsigned short* wp = wqkvt + ncol*192 + lg*8;
        #pragma unroll
        for (int ks = 0; ks < 6; ++ks) {
            bf16x8 bfr = *(const bf16x8*)(wp + ks*32);
            bf16x8 a0 = *(const bf16x8*)(xn + (0*16+lr)*XS2 + ks*32 + lg*8);
            bf16x8 a1 = *(const bf16x8*)(xn + (1*16+lr)*XS2 + ks*32 + lg*8);
            bf16x8 a2 = *(const bf16x8*)(xn + (2*16+lr)*XS2 + ks*32 + lg*8);
            bf16x8 a3 = *(const bf16x8*)(xn + (3*16+lr)*XS2 + ks*32 + lg*8);
            acc0 = __builtin_amdgcn_mfma_f32_16x16x32_bf16(a0, bfr, acc0, 0, 0, 0);
            acc1 = __builtin_amdgcn_mfma_f32_16x16x32_bf16(a1, bfr, acc1, 0, 0, 0);
            acc2 = __builtin_amdgcn_mfma_f32_16x16x32_bf16(a2, bfr, acc2, 0, 0, 0);
            acc3 = __builtin_amdgcn_mfma_f32_16x16x32_bf16(a3, bfr, acc3, 0, 0, 0);
        }
        float bias = qkv_b[ncol];
        const int h = ncol / 96, wo = ncol - h*96;
        #pragma unroll
        for (int mt = 0; mt < 4; ++mt) {
            f32x4 av = (mt==0) ? acc0 : (mt==1) ? acc1 : (mt==2) ? acc2 : acc3;
            #pragma unroll
            for (int r = 0; r < 4; ++r) {
                int tok = mt*16 + lg*4 + r;
                unsigned short v = f2bf(av[r] + bias);
                if (wo < 64) qk[tok*QKS + h*64 + wo] = v;
                else         vt[(h*32 + (wo-64))*VTS + tok] = v;
            }
        }
    }
    __syncthreads();

    // P4: attention. 24 units (head h, q-tile nq) over 4 waves. Swapped QK^T -> S^T.
    unsigned short* ao = xn;  // reuse: rows=q tokens, cols=h*32+d
    for (int u = wid; u < 24; u += 4) {
        const int h = u >> 2, nq = u & 3;
        const int qg = nq*16 + lr;   // this lane's q column
        // S^T = K @ Q^T : A-frag rows = k tokens, B-frag cols = q tokens
        f32x4 s0 = {0.f,0.f,0.f,0.f}, s1 = {0.f,0.f,0.f,0.f};
        f32x4 s2 = {0.f,0.f,0.f,0.f}, s3 = {0.f,0.f,0.f,0.f};
        bf16x8 qf = *(const bf16x8*)(qk + qg*QKS + h*64 + lg*8);
        bf16x8 k0 = *(const bf16x8*)(qk + (0*16+lr)*QKS + h*64 + 32 + lg*8);
        bf16x8 k1 = *(const bf16x8*)(qk + (1*16+lr)*QKS + h*64 + 32 + lg*8);
        bf16x8 k2 = *(const bf16x8*)(qk + (2*16+lr)*QKS + h*64 + 32 + lg*8);
        bf16x8 k3 = *(const bf16x8*)(qk + (3*16+lr)*QKS + h*64 + 32 + lg*8);
        s0 = __builtin_amdgcn_mfma_f32_16x16x32_bf16(k0, qf, s0, 0, 0, 0);
        s1 = __builtin_amdgcn_mfma_f32_16x16x32_bf16(k1, qf, s1, 0, 0, 0);
        s2 = __builtin_amdgcn_mfma_f32_16x16x32_bf16(k2, qf, s2, 0, 0, 0);
        s3 = __builtin_amdgcn_mfma_f32_16x16x32_bf16(k3, qf, s3, 0, 0, 0);
        // bias + scale; lane holds 16 scores for column q (k = mk*16 + lg*4 + r)
        const float* bp = biasfp + (size_t)(h*64 + qg)*64 + lg*4;
        float sv[4][4];
        float mx = -3.0e38f;
        #pragma unroll
        for (int mk = 0; mk < 4; ++mk) {
            f32x4 sa = (mk==0) ? s0 : (mk==1) ? s1 : (mk==2) ? s2 : s3;
            float4 b4 = *(const float4*)(bp + mk*16);
            sv[mk][0] = sa[0] * 0.17677669529663687f + b4.x;
            sv[mk][1] = sa[1] * 0.17677669529663687f + b4.y;
            sv[mk][2] = sa[2] * 0.17677669529663687f + b4.z;
            sv[mk][3] = sa[3] * 0.17677669529663687f + b4.w;
            #pragma unroll
            for (int r = 0; r < 4; ++r) mx = fmaxf(mx, sv[mk][r]);
        }
        mx = fmaxf(mx, __shfl_xor(mx, 16, 64));
        mx = fmaxf(mx, __shfl_xor(mx, 32, 64));
        float sum = 0.f;
        #pragma unroll
        for (int mk = 0; mk < 4; ++mk)
            #pragma unroll
            for (int r = 0; r < 4; ++r) { sv[mk][r] = __expf(sv[mk][r] - mx); sum += sv[mk][r]; }
        sum += __shfl_xor(sum, 16, 64);
        sum += __shfl_xor(sum, 32, 64);
        float inv = 1.f / sum;
        // write normalized P (bf16): pl[wave][q=lr][k]
        unsigned short* pw = pl + (wid*16 + lr)*PLS;
        #pragma unroll
        for (int mk = 0; mk < 4; ++mk)
            #pragma unroll
            for (int r = 0; r < 4; ++r) pw[mk*16 + lg*4 + r] = f2bf(sv[mk][r] * inv);
        // PV: out^T[d][q] = V^T @ P^T. A-frag rows=d (vt), B-frag cols=q (pl).
        #pragma unroll
        for (int dt = 0; dt < 2; ++dt) {
            f32x4 oa = {0.f,0.f,0.f,0.f};
            #pragma unroll
            for (int kk = 0; kk < 2; ++kk) {
                bf16x8 vf = *(const bf16x8*)(vt + (h*32 + dt*16 + lr)*VTS + kk*32 + lg*8);
                bf16x8 pf = *(const bf16x8*)(pl + (wid*16 + lr)*PLS + kk*32 + lg*8);
                oa = __builtin_amdgcn_mfma_f32_16x16x32_bf16(vf, pf, oa, 0, 0, 0);
            }
            #pragma unroll
            for (int r = 0; r < 4; ++r)
                ao[(nq*16 + lr)*XS2 + h*32 + dt*16 + lg*4 + r] = f2bf(oa[r]);
        }
    }
    __syncthreads();

    // P5: proj 64x192 = ao(64x192) @ proj_w + bias + shortcut -> x2 (bf16)
    for (int nt = 0; nt < 3; ++nt) {
        const int ncol = (wid*3 + nt)*16 + lr;
        f32x4 acc0 = {0.f,0.f,0.f,0.f}, acc1 = {0.f,0.f,0.f,0.f};
        f32x4 acc2 = {0.f,0.f,0.f,0.f}, acc3 = {0.f,0.f,0.f,0.f};
        const unsigned short* wp = wprojt + ncol*192 + lg*8;
        #pragma unroll
        for (int ks = 0; ks < 6; ++ks) {
            bf16x8 bfr = *(const bf16x8*)(wp + ks*32);
            bf16x8 a0 = *(const bf16x8*)(ao + (0*16+lr)*XS2 + ks*32 + lg*8);
            bf16x8 a1 = *(const bf16x8*)(ao + (1*16+lr)*XS2 + ks*32 + lg*8);
            bf16x8 a2 = *(const bf16x8*)(ao + (2*16+lr)*XS2 + ks*32 + lg*8);
            bf16x8 a3 = *(const bf16x8*)(ao + (3*16+lr)*XS2 + ks*32 + lg*8);
            acc0 = __builtin_amdgcn_mfma_f32_16x16x32_bf16(a0, bfr, acc0, 0, 0, 0);
            acc1 = __builtin_amdgcn_mfma_f32_16x16x32_bf16(a1, bfr, acc1, 0, 0, 0);
            acc2 = __builtin_amdgcn_mfma_f32_16x16x32_bf16(a2, bfr, acc2, 0, 0, 0);
            acc3 = __builtin_amdgcn_mfma_f32_16x16x32_bf16(a3, bfr, acc3, 0, 0, 0);
        }
        float bias = proj_b[ncol];
        #pragma unroll
        for (int mt = 0; mt < 4; ++mt) {
            f32x4 av = (mt==0) ? acc0 : (mt==1) ? acc1 : (mt==2) ? acc2 : acc3;
            #pragma unroll
            for (int r = 0; r < 4; ++r) {
                int tok = mt*16 + lg*4 + r;
                if (tok >= NT) continue;
                int gh = wi*WSZ + tok/WSZ, gw = wj*WSZ + tok%WSZ;
                if (gh >= IMG || gw >= IMG) continue;
                size_t g = (base + (size_t)(gh*IMG + gw))*C + ncol;
                x2[g] = f2bf(av[r] + bias + x[g]);
            }
        }
    }
}

// -------- K2 (MFMA): conv3x3+BN -> x3 ; LN2 ; fc1+GELU ; fc2 + residual -> out --------
#define X3S 200
#define H1S 776
__global__ __launch_bounds__(256) void conv_mlp_mfma(
    const unsigned short* __restrict__ x2,
    const float* __restrict__ conv_w,
    const float* __restrict__ bn_g, const float* __restrict__ bn_b,
    const float* __restrict__ bn_m, const float* __restrict__ bn_v,
    const float* __restrict__ ln2_w, const float* __restrict__ ln2_b,
    const unsigned short* __restrict__ wfc1t, const float* __restrict__ fc1_b,
    const unsigned short* __restrict__ wfc2t, const float* __restrict__ fc2_b,
    float* __restrict__ out)
{
    extern __shared__ char smem[];
    unsigned short* x3 = (unsigned short*)smem;             // [32][X3S]
    unsigned short* xn = (unsigned short*)(smem + 12800);   // [32][X3S]
    unsigned short* h1 = (unsigned short*)(smem + 25600);   // [32][H1S]
    float* stats = (float*)(smem + 75264);                  // [32][2]

    const int tid  = threadIdx.x;
    const int base = blockIdx.x * 32;
    const int b    = base >> 12;
    const int n0   = base & 4095;
    const int hh   = n0 >> 6;
    const int w0v  = n0 & 63;
    const size_t ibase = (size_t)b * 4096;

    for (int idx = tid; idx < 32*C; idx += 256) {
        int lt = idx / C, c = idx - lt*C;
        int ww = w0v + lt;
        float acc = 0.f;
        #pragma unroll
        for (int kh = -1; kh <= 1; ++kh) {
            int h2 = hh + kh;
            if (h2 < 0 || h2 >= IMG) continue;
            #pragma unroll
            for (int kw = -1; kw <= 1; ++kw) {
                int w2 = ww + kw;
                if (w2 < 0 || w2 >= IMG) continue;
                acc += bf2f(x2[(ibase + (size_t)(h2*IMG + w2))*C + c]) *
                       conv_w[c*9 + (kh+1)*3 + (kw+1)];
            }
        }
        float scale = bn_g[c] * rsqrtf(bn_v[c] + 1e-5f);
        x3[lt*X3S + c] = f2bf(acc * scale + (bn_b[c] - bn_m[c] * scale));
    }
    __syncthreads();

    {
        int lt = tid >> 3, sl = tid & 7;
        float s = 0.f, s2 = 0.f;
        for (int c = sl; c < C; c += 8) {
            float v = bf2f(x3[lt*X3S + c]);
            s += v; s2 += v*v;
        }
        #pragma unroll
        for (int msk = 1; msk < 8; msk <<= 1) {
            s  += __shfl_xor(s,  msk, 64);
            s2 += __shfl_xor(s2, msk, 64);
        }
        if (sl == 0) {
            float m = s * (1.f/C), var = s2 * (1.f/C) - m*m;
            stats[2*lt]   = m;
            stats[2*lt+1] = rsqrtf(var + 1e-5f);
        }
    }
    __syncthreads();

    for (int idx = tid; idx < 32*C; idx += 256) {
        int lt = idx / C, c = idx - lt*C;
        float v = bf2f(x3[lt*X3S + c]);
        xn[lt*X3S + c] = f2bf((v - stats[2*lt]) * stats[2*lt+1] * ln2_w[c] + ln2_b[c]);
    }
    __syncthreads();

    const int wid = tid >> 6, l = tid & 63, lr = l & 15, lk = l >> 4;
    {
        const int nbase = wid * 192;
        for (int nt = 0; nt < 12; ++nt) {
            const int ncol = nbase + nt*16 + lr;
            f32x4 a0 = {0.f,0.f,0.f,0.f}, a1 = {0.f,0.f,0.f,0.f};
            const unsigned short* wp  = wfc1t + ncol*C + lk*8;
            const unsigned short* xp0 = xn + lr*X3S + lk*8;
            const unsigned short* xp1 = xn + (16+lr)*X3S + lk*8;
            #pragma unroll
            for (int ks = 0; ks < 6; ++ks) {
                bf16x8 bfr = *(const bf16x8*)(wp  + ks*32);
                bf16x8 af0 = *(const bf16x8*)(xp0 + ks*32);
                bf16x8 af1 = *(const bf16x8*)(xp1 + ks*32);
                a0 = __builtin_amdgcn_mfma_f32_16x16x32_bf16(af0, bfr, a0, 0, 0, 0);
                a1 = __builtin_amdgcn_mfma_f32_16x16x32_bf16(af1, bfr, a1, 0, 0, 0);
            }
            float bias = fc1_b[ncol];
            #pragma unroll
            for (int r = 0; r < 4; ++r) {
                int row0 = lk*4 + r;
                h1[row0*H1S + ncol]      = f2bf(gelu_f(a0[r] + bias));
                h1[(row0+16)*H1S + ncol] = f2bf(gelu_f(a1[r] + bias));
            }
        }
    }
    __syncthreads();

    {
        const int nb2 = wid * 48;
        f32x4 acc0[3] = {{0.f,0.f,0.f,0.f},{0.f,0.f,0.f,0.f},{0.f,0.f,0.f,0.f}};
        f32x4 acc1[3] = {{0.f,0.f,0.f,0.f},{0.f,0.f,0.f,0.f},{0.f,0.f,0.f,0.f}};
        const unsigned short* hp0 = h1 + lr*H1S + lk*8;
        const unsigned short* hp1 = h1 + (16+lr)*H1S + lk*8;
        const unsigned short* wp0 = wfc2t + (nb2 + 0*16 + lr)*768 + lk*8;
        const unsigned short* wp1 = wfc2t + (nb2 + 1*16 + lr)*768 + lk*8;
        const unsigned short* wp2 = wfc2t + (nb2 + 2*16 + lr)*768 + lk*8;
        #pragma unroll 4
        for (int ks = 0; ks < 24; ++ks) {
            bf16x8 af0 = *(const bf16x8*)(hp0 + ks*32);
            bf16x8 af1 = *(const bf16x8*)(hp1 + ks*32);
            bf16x8 b0  = *(const bf16x8*)(wp0 + ks*32);
            bf16x8 b1  = *(const bf16x8*)(wp1 + ks*32);
            bf16x8 b2  = *(const bf16x8*)(wp2 + ks*32);
            acc0[0] = __builtin_amdgcn_mfma_f32_16x16x32_bf16(af0, b0, acc0[0], 0, 0, 0);
            acc1[0] = __builtin_amdgcn_mfma_f32_16x16x32_bf16(af1, b0, acc1[0], 0, 0, 0);
            acc0[1] = __builtin_amdgcn_mfma_f32_16x16x32_bf16(af0, b1, acc0[1], 0, 0, 0);
            acc1[1] = __builtin_amdgcn_mfma_f32_16x16x32_bf16(af1, b1, acc1[1], 0, 0, 0);
            acc0[2] = __builtin_amdgcn_mfma_f32_16x16x32_bf16(af0, b2, acc0[2], 0, 0, 0);
            acc1[2] = __builtin_amdgcn_mfma_f32_16x16x32_bf16(af1, b2, acc1[2], 0, 0, 0);
        }
        #pragma unroll
        for (int n = 0; n < 3; ++n) {
            int col = nb2 + n*16 + lr;
            float bias = fc2_b[col];
            #pragma unroll
            for (int r = 0; r < 4; ++r) {
                int row0 = lk*4 + r;
                float v0 = acc0[n][r] + bias + bf2f(x3[row0*X3S + col]);
                float v1 = acc1[n][r] + bias + bf2f(x3[(row0+16)*X3S + col]);
                out[(size_t)(base + row0) * C + col]      = v0;
                out[(size_t)(base + row0 + 16) * C + col] = v1;
            }
        }
    }
}

extern "C" void kernel_launch(void* const* d_in, const int* in_sizes, int n_in,
                              void* d_out, int out_size, void* d_ws, size_t ws_size,
                              hipStream_t stream)
{
    const float* x      = (const float*)d_in[0];
    const float* ln1_w  = (const float*)d_in[1];
    const float* ln1_b  = (const float*)d_in[2];
    const float* qkv_w  = (const float*)d_in[3];
    const float* qkv_b  = (const float*)d_in[4];
    const float* biases = (const float*)d_in[5];
    const float* proj_w = (const float*)d_in[6];
    const float* proj_b = (const float*)d_in[7];
    const float* conv_w = (const float*)d_in[8];
    const float* bn_g   = (const float*)d_in[9];
    const float* bn_b   = (const float*)d_in[10];
    const float* bn_m   = (const float*)d_in[11];
    const float* bn_v   = (const float*)d_in[12];
    const float* ln2_w  = (const float*)d_in[13];
    const float* ln2_b  = (const float*)d_in[14];
    const float* fc1_w  = (const float*)d_in[15];
    const float* fc1_b  = (const float*)d_in[16];
    const float* fc2_w  = (const float*)d_in[17];
    const float* fc2_b  = (const float*)d_in[18];
    const int* bidx     = (const int*)d_in[19];

    char* ws = (char*)d_ws;
    unsigned short* x2    = (unsigned short*)ws;                  // 25,165,824 B
    unsigned short* wfc1t = (unsigned short*)(ws + 25165824);     // 294,912 B
    unsigned short* wfc2t = (unsigned short*)(ws + 25460736);     // 294,912 B
    unsigned short* wqkvt = (unsigned short*)(ws + 25755648);     // 221,184 B
    unsigned short* wprojt= (unsigned short*)(ws + 25976832);     // 73,728 B
    float*          biasfp= (float*)(ws + 26050560);              // 98,304 B
    float* out = (float*)d_out;
    int noff = in_sizes[5] / NHh;

    prep_kernel<<<(442368 + NHh*64*64 + 255)/256, 256, 0, stream>>>(
        fc1_w, fc2_w, qkv_w, proj_w, biases, noff, bidx,
        wfc1t, wfc2t, wqkvt, wprojt, biasfp);

    size_t smem1 = 113152;
    hipFuncSetAttribute((const void*)attn_win_mfma,
                        hipFuncAttributeMaxDynamicSharedMemorySize, (int)smem1);
    attn_win_mfma<<<16*100, 256, smem1, stream>>>(
        x, ln1_w, ln1_b, wqkvt, qkv_b, biasfp, wprojt, proj_b, x2);

    size_t smem2 = 75520;
    hipFuncSetAttribute((const void*)conv_mlp_mfma,
                        hipFuncAttributeMaxDynamicSharedMemorySize, (int)smem2);
    conv_mlp_mfma<<<65536/32, 256, smem2, stream>>>(
        x2, conv_w, bn_g, bn_b, bn_m, bn_v, ln2_w, ln2_b,
        wfc1t, fc1_b, wfc2t, fc2_b, out);
}

// Round 7
// 577.713 us; speedup vs baseline: 6.7074x; 1.3186x over previous
//
#include <hip/hip_runtime.h>
#include <hip/hip_bf16.h>

#define C 192
#define NHh 6
#define NT 49
#define IMG 64
#define WSZ 7

#define XS2 200   // xn/ao LDS stride (bf16): 400B rows, 16B-aligned
#define QKS 392   // qk stride: 784B rows
#define VTS 72    // vt stride: 144B rows
#define PLS 72    // p_lds stride
#define H1S 776   // h1 stride: 1552B rows

typedef __attribute__((ext_vector_type(8))) short bf16x8;
typedef __attribute__((ext_vector_type(4))) float f32x4;

__device__ __forceinline__ float bf2f(unsigned short u) {
    union { unsigned int i; float f; } v; v.i = ((unsigned int)u) << 16; return v.f;
}
__device__ __forceinline__ unsigned short f2bf(float f) {
    __hip_bfloat16 h = __float2bfloat16(f);
    return *(unsigned short*)&h;
}
__device__ __forceinline__ float gelu_f(float v) {
    return 0.5f * v * (1.f + erff(v * 0.70710678118654752f));
}

// ---------------- prep: bf16-transpose weights, padded bias table, BN affine ----------------
__global__ __launch_bounds__(256) void prep_kernel(
    const float* __restrict__ fc1_w, const float* __restrict__ fc2_w,
    const float* __restrict__ qkv_w, const float* __restrict__ proj_w,
    const float* __restrict__ biases, int noff, const int* __restrict__ bidx,
    const float* __restrict__ bn_g, const float* __restrict__ bn_b,
    const float* __restrict__ bn_m, const float* __restrict__ bn_v,
    unsigned short* __restrict__ wfc1t, unsigned short* __restrict__ wfc2t,
    unsigned short* __restrict__ wqkvt, unsigned short* __restrict__ wprojt,
    float* __restrict__ biasfp, float* __restrict__ bnsc, float* __restrict__ bnsh)
{
    int i = blockIdx.x * 256 + threadIdx.x;
    if (i < 147456) {                        // wfc1t[n][k] = fc1_w[k][n], 768x192
        int n = i / 192, k = i - n * 192;
        wfc1t[i] = f2bf(fc1_w[k * 768 + n]);
    } else if (i < 294912) {                 // wfc2t[n][k] = fc2_w[k][n], 192x768
        int j = i - 147456;
        int n = j / 768, k = j - n * 768;
        wfc2t[j] = f2bf(fc2_w[k * 192 + n]);
    } else if (i < 405504) {                 // wqkvt[n][k] = qkv_w[k][n], 576x192
        int j = i - 294912;
        int n = j / 192, k = j - n * 192;
        wqkvt[j] = f2bf(qkv_w[k * 576 + n]);
    } else if (i < 442368) {                 // wprojt[n][k] = proj_w[k][n], 192x192
        int j = i - 405504;
        int n = j / 192, k = j - n * 192;
        wprojt[j] = f2bf(proj_w[k * 192 + n]);
    } else if (i < 466944) {                 // biasfp[h][q64][k64], -1e30 pad
        int j = i - 442368;
        int h = j >> 12, rem = j & 4095;
        int q = rem >> 6, k = rem & 63;
        biasfp[j] = (q < NT && k < NT) ? biases[h * noff + bidx[q * NT + k]] : -1.0e30f;
    } else if (i < 467136) {                 // BN scale/shift
        int c = i - 466944;
        float sc = bn_g[c] * rsqrtf(bn_v[c] + 1e-5f);
        bnsc[c] = sc;
        bnsh[c] = bn_b[c] - bn_m[c] * sc;
    }
}

// ---------------- K1 (MFMA, 8 waves): LN1 -> qkv -> windowed attn -> proj + residual ----------------
__global__ __launch_bounds__(512) void attn_win_mfma(
    const float* __restrict__ x,
    const float* __restrict__ ln1_w, const float* __restrict__ ln1_b,
    const unsigned short* __restrict__ wqkvt, const float* __restrict__ qkv_b,
    const float* __restrict__ biasfp,
    const unsigned short* __restrict__ wprojt, const float* __restrict__ proj_b,
    unsigned short* __restrict__ x2)
{
    extern __shared__ char smem[];
    unsigned short* xn = (unsigned short*)smem;               // [64][XS2]  25600 B (reused as ao)
    unsigned short* qk = (unsigned short*)(smem + 25600);     // [64][QKS]  50176 B
    unsigned short* vt = (unsigned short*)(smem + 75776);     // [6*32][VTS] 27648 B
    unsigned short* pl = (unsigned short*)(smem + 103424);    // [8][16][PLS] 18432 B
    float* stats = (float*)(smem + 121856);                   // [64][2] 512 B

    const int tid = threadIdx.x;
    const int blk = blockIdx.x;
    const int b  = blk / 100;
    const int wi = (blk / 10) % 10;
    const int wj = blk % 10;
    const size_t base = (size_t)b * 4096;
    const int wid = tid >> 6, lane = tid & 63, lr = lane & 15, lg = lane >> 4;

    // P0: load window (f32 -> bf16), zero-pad tokens 49..63 and OOB
    for (int idx = tid; idx < 64*48; idx += 512) {
        int t = idx / 48, c0 = (idx - t*48) * 4;
        ushort4 sv; sv.x = 0; sv.y = 0; sv.z = 0; sv.w = 0;
        if (t < NT) {
            int gh = wi*WSZ + t/WSZ, gw = wj*WSZ + t%WSZ;
            if (gh < IMG && gw < IMG) {
                float4 v = *(const float4*)(x + (base + (size_t)(gh*IMG + gw))*C + c0);
                sv.x = f2bf(v.x); sv.y = f2bf(v.y); sv.z = f2bf(v.z); sv.w = f2bf(v.w);
            }
        }
        *(ushort4*)&xn[t*XS2 + c0] = sv;
    }
    __syncthreads();

    // P1: LN1 stats, 8 lanes/token
    {
        int lt = tid >> 3, sl = tid & 7;
        float s = 0.f, s2 = 0.f;
        for (int c = sl; c < C; c += 8) {
            float v = bf2f(xn[lt*XS2 + c]);
            s += v; s2 += v*v;
        }
        #pragma unroll
        for (int msk = 1; msk < 8; msk <<= 1) {
            s  += __shfl_xor(s,  msk, 64);
            s2 += __shfl_xor(s2, msk, 64);
        }
        if (sl == 0) {
            float m = s * (1.f/C), var = s2 * (1.f/C) - m*m;
            stats[2*lt]   = m;
            stats[2*lt+1] = rsqrtf(var + 1e-5f);
        }
    }
    __syncthreads();

    // P2: normalize in place
    for (int idx = tid; idx < 64*48; idx += 512) {
        int t = idx / 48, c0 = (idx - t*48) * 4;
        float mm = stats[2*t], rr = stats[2*t+1];
        ushort4 sv = *(ushort4*)&xn[t*XS2 + c0];
        sv.x = f2bf((bf2f(sv.x) - mm) * rr * ln1_w[c0+0] + ln1_b[c0+0]);
        sv.y = f2bf((bf2f(sv.y) - mm) * rr * ln1_w[c0+1] + ln1_b[c0+1]);
        sv.z = f2bf((bf2f(sv.z) - mm) * rr * ln1_w[c0+2] + ln1_b[c0+2]);
        sv.w = f2bf((bf2f(sv.w) - mm) * rr * ln1_w[c0+3] + ln1_b[c0+3]);
        *(ushort4*)&xn[t*XS2 + c0] = sv;
    }
    __syncthreads();

    // P3: qkv GEMM 64x576; scatter C to qk / vt(transposed). 36 n-tiles over 8 waves.
    for (int nt = wid; nt < 36; nt += 8) {
        const int ncol = nt*16 + lr;
        f32x4 acc0 = {0.f,0.f,0.f,0.f}, acc1 = {0.f,0.f,0.f,0.f};
        f32x4 acc2 = {0.f,0.f,0.f,0.f}, acc3 = {0.f,0.f,0.f,0.f};
        const unsigned short* wp = wqkvt + ncol*192 + lg*8;
        #pragma unroll
        for (int ks = 0; ks < 6; ++ks) {
            bf16x8 bfr = *(const bf16x8*)(wp + ks*32);
            bf16x8 a0 = *(const bf16x8*)(xn + (0*16+lr)*XS2 + ks*32 + lg*8);
            bf16x8 a1 = *(const bf16x8*)(xn + (1*16+lr)*XS2 + ks*32 + lg*8);
            bf16x8 a2 = *(const bf16x8*)(xn + (2*16+lr)*XS2 + ks*32 + lg*8);
            bf16x8 a3 = *(const bf16x8*)(xn + (3*16+lr)*XS2 + ks*32 + lg*8);
            acc0 = __builtin_amdgcn_mfma_f32_16x16x32_bf16(a0, bfr, acc0, 0, 0, 0);
            acc1 = __builtin_amdgcn_mfma_f32_16x16x32_bf16(a1, bfr, acc1, 0, 0, 0);
            acc2 = __builtin_amdgcn_mfma_f32_16x16x32_bf16(a2, bfr, acc2, 0, 0, 0);
            acc3 = __builtin_amdgcn_mfma_f32_16x16x32_bf16(a3, bfr, acc3, 0, 0, 0);
        }
        float bias = qkv_b[ncol];
        const int h = ncol / 96, wo = ncol - h*96;
        #pragma unroll
        for (int mt = 0; mt < 4; ++mt) {
            f32x4 av = (mt==0) ? acc0 : (mt==1) ? acc1 : (mt==2) ? acc2 : acc3;
            #pragma unroll
            for (int r = 0; r < 4; ++r) {
                int tok = mt*16 + lg*4 + r;
                unsigned short v = f2bf(av[r] + bias);
                if (wo < 64) qk[tok*QKS + h*64 + wo] = v;
                else         vt[(h*32 + (wo-64))*VTS + tok] = v;
            }
        }
    }
    __syncthreads();

    // P4: attention. 24 units (h, nq) over 8 waves (3 each). Swapped QK^T -> S^T.
    unsigned short* ao = xn;
    for (int u = wid; u < 24; u += 8) {
        const int h = u >> 2, nq = u & 3;
        const int qg = nq*16 + lr;
        f32x4 s0 = {0.f,0.f,0.f,0.f}, s1 = {0.f,0.f,0.f,0.f};
        f32x4 s2 = {0.f,0.f,0.f,0.f}, s3 = {0.f,0.f,0.f,0.f};
        bf16x8 qf = *(const bf16x8*)(qk + qg*QKS + h*64 + lg*8);
        bf16x8 k0 = *(const bf16x8*)(qk + (0*16+lr)*QKS + h*64 + 32 + lg*8);
        bf16x8 k1 = *(const bf16x8*)(qk + (1*16+lr)*QKS + h*64 + 32 + lg*8);
        bf16x8 k2 = *(const bf16x8*)(qk + (2*16+lr)*QKS + h*64 + 32 + lg*8);
        bf16x8 k3 = *(const bf16x8*)(qk + (3*16+lr)*QKS + h*64 + 32 + lg*8);
        s0 = __builtin_amdgcn_mfma_f32_16x16x32_bf16(k0, qf, s0, 0, 0, 0);
        s1 = __builtin_amdgcn_mfma_f32_16x16x32_bf16(k1, qf, s1, 0, 0, 0);
        s2 = __builtin_amdgcn_mfma_f32_16x16x32_bf16(k2, qf, s2, 0, 0, 0);
        s3 = __builtin_amdgcn_mfma_f32_16x16x32_bf16(k3, qf, s3, 0, 0, 0);
        const float* bp = biasfp + (size_t)(h*64 + qg)*64 + lg*4;
        float sv[4][4];
        float mx = -3.0e38f;
        #pragma unroll
        for (int mk = 0; mk < 4; ++mk) {
            f32x4 sa = (mk==0) ? s0 : (mk==1) ? s1 : (mk==2) ? s2 : s3;
            float4 b4 = *(const float4*)(bp + mk*16);
            sv[mk][0] = sa[0] * 0.17677669529663687f + b4.x;
            sv[mk][1] = sa[1] * 0.17677669529663687f + b4.y;
            sv[mk][2] = sa[2] * 0.17677669529663687f + b4.z;
            sv[mk][3] = sa[3] * 0.17677669529663687f + b4.w;
            #pragma unroll
            for (int r = 0; r < 4; ++r) mx = fmaxf(mx, sv[mk][r]);
        }
        mx = fmaxf(mx, __shfl_xor(mx, 16, 64));
        mx = fmaxf(mx, __shfl_xor(mx, 32, 64));
        float sum = 0.f;
        #pragma unroll
        for (int mk = 0; mk < 4; ++mk)
            #pragma unroll
            for (int r = 0; r < 4; ++r) { sv[mk][r] = __expf(sv[mk][r] - mx); sum += sv[mk][r]; }
        sum += __shfl_xor(sum, 16, 64);
        sum += __shfl_xor(sum, 32, 64);
        float inv = 1.f / sum;
        unsigned short* pw = pl + (wid*16 + lr)*PLS;
        #pragma unroll
        for (int mk = 0; mk < 4; ++mk)
            #pragma unroll
            for (int r = 0; r < 4; ++r) pw[mk*16 + lg*4 + r] = f2bf(sv[mk][r] * inv);
        #pragma unroll
        for (int dt = 0; dt < 2; ++dt) {
            f32x4 oa = {0.f,0.f,0.f,0.f};
            #pragma unroll
            for (int kk = 0; kk < 2; ++kk) {
                bf16x8 vf = *(const bf16x8*)(vt + (h*32 + dt*16 + lr)*VTS + kk*32 + lg*8);
                bf16x8 pf = *(const bf16x8*)(pl + (wid*16 + lr)*PLS + kk*32 + lg*8);
                oa = __builtin_amdgcn_mfma_f32_16x16x32_bf16(vf, pf, oa, 0, 0, 0);
            }
            #pragma unroll
            for (int r = 0; r < 4; ++r)
                ao[(nq*16 + lr)*XS2 + h*32 + dt*16 + lg*4 + r] = f2bf(oa[r]);
        }
    }
    __syncthreads();

    // P5: proj + bias + shortcut -> x2 (bf16). 12 n-tiles over 8 waves.
    for (int nt = wid; nt < 12; nt += 8) {
        const int ncol = nt*16 + lr;
        f32x4 acc0 = {0.f,0.f,0.f,0.f}, acc1 = {0.f,0.f,0.f,0.f};
        f32x4 acc2 = {0.f,0.f,0.f,0.f}, acc3 = {0.f,0.f,0.f,0.f};
        const unsigned short* wp = wprojt + ncol*192 + lg*8;
        #pragma unroll
        for (int ks = 0; ks < 6; ++ks) {
            bf16x8 bfr = *(const bf16x8*)(wp + ks*32);
            bf16x8 a0 = *(const bf16x8*)(ao + (0*16+lr)*XS2 + ks*32 + lg*8);
            bf16x8 a1 = *(const bf16x8*)(ao + (1*16+lr)*XS2 + ks*32 + lg*8);
            bf16x8 a2 = *(const bf16x8*)(ao + (2*16+lr)*XS2 + ks*32 + lg*8);
            bf16x8 a3 = *(const bf16x8*)(ao + (3*16+lr)*XS2 + ks*32 + lg*8);
            acc0 = __builtin_amdgcn_mfma_f32_16x16x32_bf16(a0, bfr, acc0, 0, 0, 0);
            acc1 = __builtin_amdgcn_mfma_f32_16x16x32_bf16(a1, bfr, acc1, 0, 0, 0);
            acc2 = __builtin_amdgcn_mfma_f32_16x16x32_bf16(a2, bfr, acc2, 0, 0, 0);
            acc3 = __builtin_amdgcn_mfma_f32_16x16x32_bf16(a3, bfr, acc3, 0, 0, 0);
        }
        float bias = proj_b[ncol];
        #pragma unroll
        for (int mt = 0; mt < 4; ++mt) {
            f32x4 av = (mt==0) ? acc0 : (mt==1) ? acc1 : (mt==2) ? acc2 : acc3;
            #pragma unroll
            for (int r = 0; r < 4; ++r) {
                int tok = mt*16 + lg*4 + r;
                if (tok >= NT) continue;
                int gh = wi*WSZ + tok/WSZ, gw = wj*WSZ + tok%WSZ;
                if (gh >= IMG || gw >= IMG) continue;
                size_t g = (base + (size_t)(gh*IMG + gw))*C + ncol;
                x2[g] = f2bf(av[r] + bias + x[g]);
            }
        }
    }
}

// -------- K2a: depthwise conv3x3 + BN -> x3 (f32, stored in d_out). Zero LDS, streaming. --------
__global__ __launch_bounds__(256) void conv_bn_kernel(
    const unsigned short* __restrict__ x2,
    const float* __restrict__ conv_w,
    const float* __restrict__ bnsc, const float* __restrict__ bnsh,
    float* __restrict__ x3out)
{
    const int base = blockIdx.x * 16;
    const int b    = base >> 12;
    const int n0   = base & 4095;
    const size_t ibase = (size_t)b * 4096;

    for (int q = threadIdx.x; q < 16*48; q += 256) {
        int lt = q / 48, c0 = (q - lt*48) * 4;
        int n = n0 + lt, hh = n >> 6, ww = n & 63;
        float a0 = 0.f, a1 = 0.f, a2 = 0.f, a3 = 0.f;
        #pragma unroll
        for (int kh = -1; kh <= 1; ++kh) {
            int h2 = hh + kh;
            if (h2 < 0 || h2 >= IMG) continue;
            #pragma unroll
            for (int kw = -1; kw <= 1; ++kw) {
                int w2 = ww + kw;
                if (w2 < 0 || w2 >= IMG) continue;
                ushort4 v = *(const ushort4*)(x2 + (ibase + (size_t)(h2*IMG + w2))*C + c0);
                int tap = (kh+1)*3 + (kw+1);
                a0 += bf2f(v.x) * conv_w[(c0+0)*9 + tap];
                a1 += bf2f(v.y) * conv_w[(c0+1)*9 + tap];
                a2 += bf2f(v.z) * conv_w[(c0+2)*9 + tap];
                a3 += bf2f(v.w) * conv_w[(c0+3)*9 + tap];
            }
        }
        float4 o;
        o.x = a0 * bnsc[c0+0] + bnsh[c0+0];
        o.y = a1 * bnsc[c0+1] + bnsh[c0+1];
        o.z = a2 * bnsc[c0+2] + bnsh[c0+2];
        o.w = a3 * bnsc[c0+3] + bnsh[c0+3];
        *(float4*)(x3out + ((size_t)base + lt)*C + c0) = o;
    }
}

// -------- K2b (MFMA): LN2 (from global x3) ; fc1+GELU ; fc2 + residual -> out (in place) --------
__global__ __launch_bounds__(256) void mlp_mfma(
    float* xout,   // = d_out: holds x3 on entry, final output on exit (NOT restrict)
    const float* __restrict__ ln2_w, const float* __restrict__ ln2_b,
    const unsigned short* __restrict__ wfc1t, const float* __restrict__ fc1_b,
    const unsigned short* __restrict__ wfc2t, const float* __restrict__ fc2_b)
{
    extern __shared__ char smem[];
    unsigned short* xnl = (unsigned short*)smem;            // [32][XS2] 12800 B
    unsigned short* h1  = (unsigned short*)(smem + 12800);  // [32][H1S] 49664 B
    float* stats = (float*)(smem + 62464);                  // [32][2]

    const int tid  = threadIdx.x;
    const int base = blockIdx.x * 32;

    // P0: LN2 stats from global x3 (8 lanes/token, float4)
    {
        int lt = tid >> 3, sl = tid & 7;
        const float* xr = xout + ((size_t)base + lt)*C;
        float s = 0.f, s2 = 0.f;
        for (int c = sl*4; c < C; c += 32) {
            float4 v = *(const float4*)(xr + c);
            s  += v.x + v.y + v.z + v.w;
            s2 += v.x*v.x + v.y*v.y + v.z*v.z + v.w*v.w;
        }
        #pragma unroll
        for (int msk = 1; msk < 8; msk <<= 1) {
            s  += __shfl_xor(s,  msk, 64);
            s2 += __shfl_xor(s2, msk, 64);
        }
        if (sl == 0) {
            float m = s * (1.f/C), var = s2 * (1.f/C) - m*m;
            stats[2*lt]   = m;
            stats[2*lt+1] = rsqrtf(var + 1e-5f);
        }
    }
    __syncthreads();

    // P1: normalize -> xnl (bf16 LDS)
    for (int idx = tid; idx < 32*48; idx += 256) {
        int lt = idx / 48, c0 = (idx - lt*48) * 4;
        float mm = stats[2*lt], rr = stats[2*lt+1];
        float4 v = *(const float4*)(xout + ((size_t)base + lt)*C + c0);
        ushort4 sv;
        sv.x = f2bf((v.x - mm) * rr * ln2_w[c0+0] + ln2_b[c0+0]);
        sv.y = f2bf((v.y - mm) * rr * ln2_w[c0+1] + ln2_b[c0+1]);
        sv.z = f2bf((v.z - mm) * rr * ln2_w[c0+2] + ln2_b[c0+2]);
        sv.w = f2bf((v.w - mm) * rr * ln2_w[c0+3] + ln2_b[c0+3]);
        *(ushort4*)&xnl[lt*XS2 + c0] = sv;
    }
    __syncthreads();

    const int wid = tid >> 6, l = tid & 63, lr = l & 15, lk = l >> 4;

    // P2: fc1 + GELU -> h1
    {
        const int nbase = wid * 192;
        for (int nt = 0; nt < 12; ++nt) {
            const int ncol = nbase + nt*16 + lr;
            f32x4 a0 = {0.f,0.f,0.f,0.f}, a1 = {0.f,0.f,0.f,0.f};
            const unsigned short* wp  = wfc1t + ncol*C + lk*8;
            const unsigned short* xp0 = xnl + lr*XS2 + lk*8;
            const unsigned short* xp1 = xnl + (16+lr)*XS2 + lk*8;
            #pragma unroll
            for (int ks = 0; ks < 6; ++ks) {
                bf16x8 bfr = *(const bf16x8*)(wp  + ks*32);
                bf16x8 af0 = *(const bf16x8*)(xp0 + ks*32);
                bf16x8 af1 = *(const bf16x8*)(xp1 + ks*32);
                a0 = __builtin_amdgcn_mfma_f32_16x16x32_bf16(af0, bfr, a0, 0, 0, 0);
                a1 = __builtin_amdgcn_mfma_f32_16x16x32_bf16(af1, bfr, a1, 0, 0, 0);
            }
            float bias = fc1_b[ncol];
            #pragma unroll
            for (int r = 0; r < 4; ++r) {
                int row0 = lk*4 + r;
                h1[row0*H1S + ncol]      = f2bf(gelu_f(a0[r] + bias));
                h1[(row0+16)*H1S + ncol] = f2bf(gelu_f(a1[r] + bias));
            }
        }
    }
    __syncthreads();

    // P3: fc2 + bias + residual (f32 x3 from global) -> out in place
    {
        const int nb2 = wid * 48;
        f32x4 acc0[3] = {{0.f,0.f,0.f,0.f},{0.f,0.f,0.f,0.f},{0.f,0.f,0.f,0.f}};
        f32x4 acc1[3] = {{0.f,0.f,0.f,0.f},{0.f,0.f,0.f,0.f},{0.f,0.f,0.f,0.f}};
        const unsigned short* hp0 = h1 + lr*H1S + lk*8;
        const unsigned short* hp1 = h1 + (16+lr)*H1S + lk*8;
        const unsigned short* wp0 = wfc2t + (nb2 + 0*16 + lr)*768 + lk*8;
        const unsigned short* wp1 = wfc2t + (nb2 + 1*16 + lr)*768 + lk*8;
        const unsigned short* wp2 = wfc2t + (nb2 + 2*16 + lr)*768 + lk*8;
        #pragma unroll 4
        for (int ks = 0; ks < 24; ++ks) {
            bf16x8 af0 = *(const bf16x8*)(hp0 + ks*32);
            bf16x8 af1 = *(const bf16x8*)(hp1 + ks*32);
            bf16x8 b0  = *(const bf16x8*)(wp0 + ks*32);
            bf16x8 b1  = *(const bf16x8*)(wp1 + ks*32);
            bf16x8 b2  = *(const bf16x8*)(wp2 + ks*32);
            acc0[0] = __builtin_amdgcn_mfma_f32_16x16x32_bf16(af0, b0, acc0[0], 0, 0, 0);
            acc1[0] = __builtin_amdgcn_mfma_f32_16x16x32_bf16(af1, b0, acc1[0], 0, 0, 0);
            acc0[1] = __builtin_amdgcn_mfma_f32_16x16x32_bf16(af0, b1, acc0[1], 0, 0, 0);
            acc1[1] = __builtin_amdgcn_mfma_f32_16x16x32_bf16(af1, b1, acc1[1], 0, 0, 0);
            acc0[2] = __builtin_amdgcn_mfma_f32_16x16x32_bf16(af0, b2, acc0[2], 0, 0, 0);
            acc1[2] = __builtin_amdgcn_mfma_f32_16x16x32_bf16(af1, b2, acc1[2], 0, 0, 0);
        }
        #pragma unroll
        for (int n = 0; n < 3; ++n) {
            int col = nb2 + n*16 + lr;
            float bias = fc2_b[col];
            #pragma unroll
            for (int r = 0; r < 4; ++r) {
                int row0 = lk*4 + r;
                size_t g0 = (size_t)(base + row0) * C + col;
                size_t g1 = (size_t)(base + row0 + 16) * C + col;
                float v0 = acc0[n][r] + bias + xout[g0];
                float v1 = acc1[n][r] + bias + xout[g1];
                xout[g0] = v0;
                xout[g1] = v1;
            }
        }
    }
}

extern "C" void kernel_launch(void* const* d_in, const int* in_sizes, int n_in,
                              void* d_out, int out_size, void* d_ws, size_t ws_size,
                              hipStream_t stream)
{
    const float* x      = (const float*)d_in[0];
    const float* ln1_w  = (const float*)d_in[1];
    const float* ln1_b  = (const float*)d_in[2];
    const float* qkv_w  = (const float*)d_in[3];
    const float* qkv_b  = (const float*)d_in[4];
    const float* biases = (const float*)d_in[5];
    const float* proj_w = (const float*)d_in[6];
    const float* proj_b = (const float*)d_in[7];
    const float* conv_w = (const float*)d_in[8];
    const float* bn_g   = (const float*)d_in[9];
    const float* bn_b   = (const float*)d_in[10];
    const float* bn_m   = (const float*)d_in[11];
    const float* bn_v   = (const float*)d_in[12];
    const float* ln2_w  = (const float*)d_in[13];
    const float* ln2_b  = (const float*)d_in[14];
    const float* fc1_w  = (const float*)d_in[15];
    const float* fc1_b  = (const float*)d_in[16];
    const float* fc2_w  = (const float*)d_in[17];
    const float* fc2_b  = (const float*)d_in[18];
    const int* bidx     = (const int*)d_in[19];

    char* ws = (char*)d_ws;
    unsigned short* x2    = (unsigned short*)ws;                  // 25,165,824 B
    unsigned short* wfc1t = (unsigned short*)(ws + 25165824);     // 294,912 B
    unsigned short* wfc2t = (unsigned short*)(ws + 25460736);     // 294,912 B
    unsigned short* wqkvt = (unsigned short*)(ws + 25755648);     // 221,184 B
    unsigned short* wprojt= (unsigned short*)(ws + 25976832);     // 73,728 B
    float*          biasfp= (float*)(ws + 26050560);              // 98,304 B
    float*          bnsc  = (float*)(ws + 26148864);              // 768 B
    float*          bnsh  = (float*)(ws + 26149632);              // 768 B
    float* out = (float*)d_out;
    int noff = in_sizes[5] / NHh;

    prep_kernel<<<(467136 + 255)/256, 256, 0, stream>>>(
        fc1_w, fc2_w, qkv_w, proj_w, biases, noff, bidx,
        bn_g, bn_b, bn_m, bn_v,
        wfc1t, wfc2t, wqkvt, wprojt, biasfp, bnsc, bnsh);

    size_t smem1 = 122368;
    hipFuncSetAttribute((const void*)attn_win_mfma,
                        hipFuncAttributeMaxDynamicSharedMemorySize, (int)smem1);
    attn_win_mfma<<<16*100, 512, smem1, stream>>>(
        x, ln1_w, ln1_b, wqkvt, qkv_b, biasfp, wprojt, proj_b, x2);

    conv_bn_kernel<<<65536/16, 256, 0, stream>>>(x2, conv_w, bnsc, bnsh, out);

    size_t smem2 = 62720;
    hipFuncSetAttribute((const void*)mlp_mfma,
                        hipFuncAttributeMaxDynamicSharedMemorySize, (int)smem2);
    mlp_mfma<<<65536/32, 256, smem2, stream>>>(
        out, ln2_w, ln2_b, wfc1t, fc1_b, wfc2t, fc2_b);
}

// Round 8
// 552.185 us; speedup vs baseline: 7.0175x; 1.0462x over previous
//
#include <hip/hip_runtime.h>
#include <hip/hip_bf16.h>

#define C 192
#define NHh 6
#define NT 49
#define IMG 64
#define WSZ 7

#define XS2 200   // xn/ao LDS stride (bf16)
#define QKS 392
#define VTS 72
#define PLS 72
#define X3S 200   // conv_mlp2 row stride (bf16)

typedef __attribute__((ext_vector_type(8))) short bf16x8;
typedef __attribute__((ext_vector_type(4))) float f32x4;

__device__ __forceinline__ float bf2f(unsigned short u) {
    union { unsigned int i; float f; } v; v.i = ((unsigned int)u) << 16; return v.f;
}
__device__ __forceinline__ unsigned short f2bf(float f) {
    __hip_bfloat16 h = __float2bfloat16(f);
    return *(unsigned short*)&h;
}
__device__ __forceinline__ float gelu_f(float v) {
    return 0.5f * v * (1.f + erff(v * 0.70710678118654752f));
}

// ---------------- prep: transposes with COALESCED reads / scattered writes ----------------
__global__ __launch_bounds__(256) void prep_kernel(
    const float* __restrict__ fc1_w, const float* __restrict__ fc2_w,
    const float* __restrict__ qkv_w, const float* __restrict__ proj_w,
    const float* __restrict__ biases, int noff, const int* __restrict__ bidx,
    const float* __restrict__ bn_g, const float* __restrict__ bn_b,
    const float* __restrict__ bn_m, const float* __restrict__ bn_v,
    unsigned short* __restrict__ wfc1t, unsigned short* __restrict__ wfc2t,
    unsigned short* __restrict__ wqkvt, unsigned short* __restrict__ wprojt,
    float* __restrict__ biasfp, float* __restrict__ bnsc, float* __restrict__ bnsh)
{
    int i = blockIdx.x * 256 + threadIdx.x;
    if (i < 147456) {                        // read fc1_w[i] coalesced; wfc1t[n][k]=fc1_w[k][n]
        int k = i / 768, n = i - k * 768;
        wfc1t[n * 192 + k] = f2bf(fc1_w[i]);
    } else if (i < 294912) {
        int j = i - 147456;                  // read fc2_w[j]; wfc2t[n][k]
        int k = j / 192, n = j - k * 192;
        wfc2t[n * 768 + k] = f2bf(fc2_w[j]);
    } else if (i < 405504) {
        int j = i - 294912;                  // read qkv_w[j]; wqkvt[n][k]
        int k = j / 576, n = j - k * 576;
        wqkvt[n * 192 + k] = f2bf(qkv_w[j]);
    } else if (i < 442368) {
        int j = i - 405504;                  // read proj_w[j]; wprojt[n][k]
        int k = j / 192, n = j - k * 192;
        wprojt[n * 192 + k] = f2bf(proj_w[j]);
    } else if (i < 466944) {                 // biasfp[h][q64][k64], -1e30 pad
        int j = i - 442368;
        int h = j >> 12, rem = j & 4095;
        int q = rem >> 6, k = rem & 63;
        biasfp[j] = (q < NT && k < NT) ? biases[h * noff + bidx[q * NT + k]] : -1.0e30f;
    } else if (i < 467136) {                 // BN scale/shift
        int c = i - 466944;
        float sc = bn_g[c] * rsqrtf(bn_v[c] + 1e-5f);
        bnsc[c] = sc;
        bnsh[c] = bn_b[c] - bn_m[c] * sc;
    }
}

// ---------------- K1 (MFMA, 8 waves): LN1 -> qkv -> windowed attn -> proj + residual ----------------
__global__ __launch_bounds__(512) void attn_win_mfma(
    const float* __restrict__ x,
    const float* __restrict__ ln1_w, const float* __restrict__ ln1_b,
    const unsigned short* __restrict__ wqkvt, const float* __restrict__ qkv_b,
    const float* __restrict__ biasfp,
    const unsigned short* __restrict__ wprojt, const float* __restrict__ proj_b,
    unsigned short* __restrict__ x2)
{
    extern __shared__ char smem[];
    unsigned short* xn = (unsigned short*)smem;               // [64][XS2]  25600 B (reused as ao)
    unsigned short* qk = (unsigned short*)(smem + 25600);     // [64][QKS]  50176 B
    unsigned short* vt = (unsigned short*)(smem + 75776);     // [6*32][VTS] 27648 B
    unsigned short* pl = (unsigned short*)(smem + 103424);    // [8][16][PLS] 18432 B
    float* stats = (float*)(smem + 121856);                   // [64][2] 512 B

    const int tid = threadIdx.x;
    const int blk = blockIdx.x;
    const int b  = blk / 100;
    const int wi = (blk / 10) % 10;
    const int wj = blk % 10;
    const size_t base = (size_t)b * 4096;
    const int wid = tid >> 6, lane = tid & 63, lr = lane & 15, lg = lane >> 4;

    // P0: load window (f32 -> bf16), zero-pad tokens 49..63 and OOB
    for (int idx = tid; idx < 64*48; idx += 512) {
        int t = idx / 48, c0 = (idx - t*48) * 4;
        ushort4 sv; sv.x = 0; sv.y = 0; sv.z = 0; sv.w = 0;
        if (t < NT) {
            int gh = wi*WSZ + t/WSZ, gw = wj*WSZ + t%WSZ;
            if (gh < IMG && gw < IMG) {
                float4 v = *(const float4*)(x + (base + (size_t)(gh*IMG + gw))*C + c0);
                sv.x = f2bf(v.x); sv.y = f2bf(v.y); sv.z = f2bf(v.z); sv.w = f2bf(v.w);
            }
        }
        *(ushort4*)&xn[t*XS2 + c0] = sv;
    }
    __syncthreads();

    // P1: LN1 stats, 8 lanes/token
    {
        int lt = tid >> 3, sl = tid & 7;
        float s = 0.f, s2 = 0.f;
        for (int c = sl; c < C; c += 8) {
            float v = bf2f(xn[lt*XS2 + c]);
            s += v; s2 += v*v;
        }
        #pragma unroll
        for (int msk = 1; msk < 8; msk <<= 1) {
            s  += __shfl_xor(s,  msk, 64);
            s2 += __shfl_xor(s2, msk, 64);
        }
        if (sl == 0) {
            float m = s * (1.f/C), var = s2 * (1.f/C) - m*m;
            stats[2*lt]   = m;
            stats[2*lt+1] = rsqrtf(var + 1e-5f);
        }
    }
    __syncthreads();

    // P2: normalize in place
    for (int idx = tid; idx < 64*48; idx += 512) {
        int t = idx / 48, c0 = (idx - t*48) * 4;
        float mm = stats[2*t], rr = stats[2*t+1];
        ushort4 sv = *(ushort4*)&xn[t*XS2 + c0];
        sv.x = f2bf((bf2f(sv.x) - mm) * rr * ln1_w[c0+0] + ln1_b[c0+0]);
        sv.y = f2bf((bf2f(sv.y) - mm) * rr * ln1_w[c0+1] + ln1_b[c0+1]);
        sv.z = f2bf((bf2f(sv.z) - mm) * rr * ln1_w[c0+2] + ln1_b[c0+2]);
        sv.w = f2bf((bf2f(sv.w) - mm) * rr * ln1_w[c0+3] + ln1_b[c0+3]);
        *(ushort4*)&xn[t*XS2 + c0] = sv;
    }
    __syncthreads();

    // P3: qkv GEMM 64x576; scatter C to qk / vt(transposed). 36 n-tiles over 8 waves.
    for (int nt = wid; nt < 36; nt += 8) {
        const int ncol = nt*16 + lr;
        f32x4 acc0 = {0.f,0.f,0.f,0.f}, acc1 = {0.f,0.f,0.f,0.f};
        f32x4 acc2 = {0.f,0.f,0.f,0.f}, acc3 = {0.f,0.f,0.f,0.f};
        const unsigned short* wp = wqkvt + ncol*192 + lg*8;
        #pragma unroll
        for (int ks = 0; ks < 6; ++ks) {
            bf16x8 bfr = *(const bf16x8*)(wp + ks*32);
            bf16x8 a0 = *(const bf16x8*)(xn + (0*16+lr)*XS2 + ks*32 + lg*8);
            bf16x8 a1 = *(const bf16x8*)(xn + (1*16+lr)*XS2 + ks*32 + lg*8);
            bf16x8 a2 = *(const bf16x8*)(xn + (2*16+lr)*XS2 + ks*32 + lg*8);
            bf16x8 a3 = *(const bf16x8*)(xn + (3*16+lr)*XS2 + ks*32 + lg*8);
            acc0 = __builtin_amdgcn_mfma_f32_16x16x32_bf16(a0, bfr, acc0, 0, 0, 0);
            acc1 = __builtin_amdgcn_mfma_f32_16x16x32_bf16(a1, bfr, acc1, 0, 0, 0);
            acc2 = __builtin_amdgcn_mfma_f32_16x16x32_bf16(a2, bfr, acc2, 0, 0, 0);
            acc3 = __builtin_amdgcn_mfma_f32_16x16x32_bf16(a3, bfr, acc3, 0, 0, 0);
        }
        float bias = qkv_b[ncol];
        const int h = ncol / 96, wo = ncol - h*96;
        #pragma unroll
        for (int mt = 0; mt < 4; ++mt) {
            f32x4 av = (mt==0) ? acc0 : (mt==1) ? acc1 : (mt==2) ? acc2 : acc3;
            #pragma unroll
            for (int r = 0; r < 4; ++r) {
                int tok = mt*16 + lg*4 + r;
                unsigned short v = f2bf(av[r] + bias);
                if (wo < 64) qk[tok*QKS + h*64 + wo] = v;
                else         vt[(h*32 + (wo-64))*VTS + tok] = v;
            }
        }
    }
    __syncthreads();

    // P4: attention. 24 units (h, nq) over 8 waves (3 each). Swapped QK^T -> S^T.
    unsigned short* ao = xn;
    for (int u = wid; u < 24; u += 8) {
        const int h = u >> 2, nq = u & 3;
        const int qg = nq*16 + lr;
        f32x4 s0 = {0.f,0.f,0.f,0.f}, s1 = {0.f,0.f,0.f,0.f};
        f32x4 s2 = {0.f,0.f,0.f,0.f}, s3 = {0.f,0.f,0.f,0.f};
        bf16x8 qf = *(const bf16x8*)(qk + qg*QKS + h*64 + lg*8);
        bf16x8 k0 = *(const bf16x8*)(qk + (0*16+lr)*QKS + h*64 + 32 + lg*8);
        bf16x8 k1 = *(const bf16x8*)(qk + (1*16+lr)*QKS + h*64 + 32 + lg*8);
        bf16x8 k2 = *(const bf16x8*)(qk + (2*16+lr)*QKS + h*64 + 32 + lg*8);
        bf16x8 k3 = *(const bf16x8*)(qk + (3*16+lr)*QKS + h*64 + 32 + lg*8);
        s0 = __builtin_amdgcn_mfma_f32_16x16x32_bf16(k0, qf, s0, 0, 0, 0);
        s1 = __builtin_amdgcn_mfma_f32_16x16x32_bf16(k1, qf, s1, 0, 0, 0);
        s2 = __builtin_amdgcn_mfma_f32_16x16x32_bf16(k2, qf, s2, 0, 0, 0);
        s3 = __builtin_amdgcn_mfma_f32_16x16x32_bf16(k3, qf, s3, 0, 0, 0);
        const float* bp = biasfp + (size_t)(h*64 + qg)*64 + lg*4;
        float sv[4][4];
        float mx = -3.0e38f;
        #pragma unroll
        for (int mk = 0; mk < 4; ++mk) {
            f32x4 sa = (mk==0) ? s0 : (mk==1) ? s1 : (mk==2) ? s2 : s3;
            float4 b4 = *(const float4*)(bp + mk*16);
            sv[mk][0] = sa[0] * 0.17677669529663687f + b4.x;
            sv[mk][1] = sa[1] * 0.17677669529663687f + b4.y;
            sv[mk][2] = sa[2] * 0.17677669529663687f + b4.z;
            sv[mk][3] = sa[3] * 0.17677669529663687f + b4.w;
            #pragma unroll
            for (int r = 0; r < 4; ++r) mx = fmaxf(mx, sv[mk][r]);
        }
        mx = fmaxf(mx, __shfl_xor(mx, 16, 64));
        mx = fmaxf(mx, __shfl_xor(mx, 32, 64));
        float sum = 0.f;
        #pragma unroll
        for (int mk = 0; mk < 4; ++mk)
            #pragma unroll
            for (int r = 0; r < 4; ++r) { sv[mk][r] = __expf(sv[mk][r] - mx); sum += sv[mk][r]; }
        sum += __shfl_xor(sum, 16, 64);
        sum += __shfl_xor(sum, 32, 64);
        float inv = 1.f / sum;
        unsigned short* pw = pl + (wid*16 + lr)*PLS;
        #pragma unroll
        for (int mk = 0; mk < 4; ++mk)
            #pragma unroll
            for (int r = 0; r < 4; ++r) pw[mk*16 + lg*4 + r] = f2bf(sv[mk][r] * inv);
        #pragma unroll
        for (int dt = 0; dt < 2; ++dt) {
            f32x4 oa = {0.f,0.f,0.f,0.f};
            #pragma unroll
            for (int kk = 0; kk < 2; ++kk) {
                bf16x8 vf = *(const bf16x8*)(vt + (h*32 + dt*16 + lr)*VTS + kk*32 + lg*8);
                bf16x8 pf = *(const bf16x8*)(pl + (wid*16 + lr)*PLS + kk*32 + lg*8);
                oa = __builtin_amdgcn_mfma_f32_16x16x32_bf16(vf, pf, oa, 0, 0, 0);
            }
            #pragma unroll
            for (int r = 0; r < 4; ++r)
                ao[(nq*16 + lr)*XS2 + h*32 + dt*16 + lg*4 + r] = f2bf(oa[r]);
        }
    }
    __syncthreads();

    // P5: proj + bias + shortcut -> x2 (bf16). 12 n-tiles over 8 waves.
    for (int nt = wid; nt < 12; nt += 8) {
        const int ncol = nt*16 + lr;
        f32x4 acc0 = {0.f,0.f,0.f,0.f}, acc1 = {0.f,0.f,0.f,0.f};
        f32x4 acc2 = {0.f,0.f,0.f,0.f}, acc3 = {0.f,0.f,0.f,0.f};
        const unsigned short* wp = wprojt + ncol*192 + lg*8;
        #pragma unroll
        for (int ks = 0; ks < 6; ++ks) {
            bf16x8 bfr = *(const bf16x8*)(wp + ks*32);
            bf16x8 a0 = *(const bf16x8*)(ao + (0*16+lr)*XS2 + ks*32 + lg*8);
            bf16x8 a1 = *(const bf16x8*)(ao + (1*16+lr)*XS2 + ks*32 + lg*8);
            bf16x8 a2 = *(const bf16x8*)(ao + (2*16+lr)*XS2 + ks*32 + lg*8);
            bf16x8 a3 = *(const bf16x8*)(ao + (3*16+lr)*XS2 + ks*32 + lg*8);
            acc0 = __builtin_amdgcn_mfma_f32_16x16x32_bf16(a0, bfr, acc0, 0, 0, 0);
            acc1 = __builtin_amdgcn_mfma_f32_16x16x32_bf16(a1, bfr, acc1, 0, 0, 0);
            acc2 = __builtin_amdgcn_mfma_f32_16x16x32_bf16(a2, bfr, acc2, 0, 0, 0);
            acc3 = __builtin_amdgcn_mfma_f32_16x16x32_bf16(a3, bfr, acc3, 0, 0, 0);
        }
        float bias = proj_b[ncol];
        #pragma unroll
        for (int mt = 0; mt < 4; ++mt) {
            f32x4 av = (mt==0) ? acc0 : (mt==1) ? acc1 : (mt==2) ? acc2 : acc3;
            #pragma unroll
            for (int r = 0; r < 4; ++r) {
                int tok = mt*16 + lg*4 + r;
                if (tok >= NT) continue;
                int gh = wi*WSZ + tok/WSZ, gw = wj*WSZ + tok%WSZ;
                if (gh >= IMG || gw >= IMG) continue;
                size_t g = (base + (size_t)(gh*IMG + gw))*C + ncol;
                x2[g] = f2bf(av[r] + bias + x[g]);
            }
        }
    }
}

// ---- fc1-chunk produce / fc2-chunk consume helpers (chunk = 192 hidden cols) ----
__device__ __forceinline__ f32x4 mfma16(bf16x8 a, bf16x8 b, f32x4 c) {
    return __builtin_amdgcn_mfma_f32_16x16x32_bf16(a, b, c, 0, 0, 0);
}

__device__ __forceinline__ void mlp_produce(
    int ch, unsigned short* buf, const unsigned short* xnl,
    const unsigned short* __restrict__ wfc1t, const float* __restrict__ fc1_b,
    int wid, int lr, int lk)
{
    bf16x8 xa0[6], xa1[6];
    #pragma unroll
    for (int ks = 0; ks < 6; ++ks) {
        xa0[ks] = *(const bf16x8*)(xnl + lr*X3S + ks*32 + lk*8);
        xa1[ks] = *(const bf16x8*)(xnl + (16+lr)*X3S + ks*32 + lk*8);
    }
    #pragma unroll
    for (int t = 0; t < 3; ++t) {
        const int nl = (wid*3 + t)*16 + lr;       // local col in chunk
        const int ncol = ch*192 + nl;             // global hidden col
        f32x4 a0 = {0.f,0.f,0.f,0.f}, a1 = {0.f,0.f,0.f,0.f};
        const unsigned short* wp = wfc1t + (size_t)ncol*192 + lk*8;
        #pragma unroll
        for (int ks = 0; ks < 6; ++ks) {
            bf16x8 bfr = *(const bf16x8*)(wp + ks*32);
            a0 = mfma16(xa0[ks], bfr, a0);
            a1 = mfma16(xa1[ks], bfr, a1);
        }
        float bias = fc1_b[ncol];
        #pragma unroll
        for (int r = 0; r < 4; ++r) {
            int row0 = lk*4 + r;
            buf[row0*X3S + nl]      = f2bf(gelu_f(a0[r] + bias));
            buf[(row0+16)*X3S + nl] = f2bf(gelu_f(a1[r] + bias));
        }
    }
}

__device__ __forceinline__ void mlp_consume(
    int ch, const unsigned short* buf,
    const unsigned short* __restrict__ wfc2t,
    f32x4* acc0, f32x4* acc1, int nb2, int lr, int lk)
{
    #pragma unroll
    for (int ks = 0; ks < 6; ++ks) {
        bf16x8 af0 = *(const bf16x8*)(buf + lr*X3S + ks*32 + lk*8);
        bf16x8 af1 = *(const bf16x8*)(buf + (16+lr)*X3S + ks*32 + lk*8);
        #pragma unroll
        for (int n = 0; n < 3; ++n) {
            bf16x8 b = *(const bf16x8*)(wfc2t + (size_t)(nb2 + n*16 + lr)*768 + ch*192 + ks*32 + lk*8);
            acc0[n] = mfma16(af0, b, acc0[n]);
            acc1[n] = mfma16(af1, b, acc1[n]);
        }
    }
}

// -------- K2 (fused, MFMA): conv3x3+BN -> x3(LDS) ; LN2 ; fc1+GELU / fc2 chunk-pipelined ; +residual -> out --------
__global__ __launch_bounds__(256) void conv_mlp2(
    const unsigned short* __restrict__ x2,
    const float* __restrict__ conv_w,
    const float* __restrict__ bnsc, const float* __restrict__ bnsh,
    const float* __restrict__ ln2_w, const float* __restrict__ ln2_b,
    const unsigned short* __restrict__ wfc1t, const float* __restrict__ fc1_b,
    const unsigned short* __restrict__ wfc2t, const float* __restrict__ fc2_b,
    float* __restrict__ out)
{
    extern __shared__ char smem[];
    unsigned short* x3  = (unsigned short*)smem;             // [32][X3S] 12800
    unsigned short* xnl = (unsigned short*)(smem + 12800);   // [32][X3S] 12800
    unsigned short* h1a = (unsigned short*)(smem + 25600);   // [32][X3S] 12800 (chunk buf A)
    unsigned short* h1b = (unsigned short*)(smem + 38400);   // [32][X3S] 12800 (chunk buf B)
    float* stats = (float*)(smem + 51200);                   // [32][2] 256

    const int tid  = threadIdx.x;
    const int base = blockIdx.x * 32;
    const int b    = base >> 12;
    const int n0   = base & 4095;
    const int hh   = n0 >> 6;
    const int w0v  = n0 & 63;
    const size_t ibase = (size_t)b * 4096;

    // P0: depthwise conv3x3 + BN -> x3 (bf16 LDS)
    for (int idx = tid; idx < 32*48; idx += 256) {
        int lt = idx / 48, c0 = (idx - lt*48) * 4;
        int ww = w0v + lt;
        float a0 = 0.f, a1 = 0.f, a2 = 0.f, a3 = 0.f;
        #pragma unroll
        for (int kh = -1; kh <= 1; ++kh) {
            int h2 = hh + kh;
            if (h2 < 0 || h2 >= IMG) continue;
            #pragma unroll
            for (int kw = -1; kw <= 1; ++kw) {
                int w2 = ww + kw;
                if (w2 < 0 || w2 >= IMG) continue;
                ushort4 v = *(const ushort4*)(x2 + (ibase + (size_t)(h2*IMG + w2))*C + c0);
                int tap = (kh+1)*3 + (kw+1);
                a0 += bf2f(v.x) * conv_w[(c0+0)*9 + tap];
                a1 += bf2f(v.y) * conv_w[(c0+1)*9 + tap];
                a2 += bf2f(v.z) * conv_w[(c0+2)*9 + tap];
                a3 += bf2f(v.w) * conv_w[(c0+3)*9 + tap];
            }
        }
        ushort4 o;
        o.x = f2bf(a0 * bnsc[c0+0] + bnsh[c0+0]);
        o.y = f2bf(a1 * bnsc[c0+1] + bnsh[c0+1]);
        o.z = f2bf(a2 * bnsc[c0+2] + bnsh[c0+2]);
        o.w = f2bf(a3 * bnsc[c0+3] + bnsh[c0+3]);
        *(ushort4*)&x3[lt*X3S + c0] = o;
    }
    __syncthreads();

    // P1: LN2 stats (8 lanes/token)
    {
        int lt = tid >> 3, sl = tid & 7;
        float s = 0.f, s2 = 0.f;
        for (int c = sl; c < C; c += 8) {
            float v = bf2f(x3[lt*X3S + c]);
            s += v; s2 += v*v;
        }
        #pragma unroll
        for (int msk = 1; msk < 8; msk <<= 1) {
            s  += __shfl_xor(s,  msk, 64);
            s2 += __shfl_xor(s2, msk, 64);
        }
        if (sl == 0) {
            float m = s * (1.f/C), var = s2 * (1.f/C) - m*m;
            stats[2*lt]   = m;
            stats[2*lt+1] = rsqrtf(var + 1e-5f);
        }
    }
    __syncthreads();

    // P2: normalize -> xnl
    for (int idx = tid; idx < 32*48; idx += 256) {
        int lt = idx / 48, c0 = (idx - lt*48) * 4;
        float mm = stats[2*lt], rr = stats[2*lt+1];
        ushort4 v = *(ushort4*)&x3[lt*X3S + c0];
        ushort4 sv;
        sv.x = f2bf((bf2f(v.x) - mm) * rr * ln2_w[c0+0] + ln2_b[c0+0]);
        sv.y = f2bf((bf2f(v.y) - mm) * rr * ln2_w[c0+1] + ln2_b[c0+1]);
        sv.z = f2bf((bf2f(v.z) - mm) * rr * ln2_w[c0+2] + ln2_b[c0+2]);
        sv.w = f2bf((bf2f(v.w) - mm) * rr * ln2_w[c0+3] + ln2_b[c0+3]);
        *(ushort4*)&xnl[lt*XS2 + c0] = sv;
    }
    __syncthreads();

    const int wid = tid >> 6, l = tid & 63, lr = l & 15, lk = l >> 4;
    const int nb2 = wid * 48;

    f32x4 acc0[3] = {{0.f,0.f,0.f,0.f},{0.f,0.f,0.f,0.f},{0.f,0.f,0.f,0.f}};
    f32x4 acc1[3] = {{0.f,0.f,0.f,0.f},{0.f,0.f,0.f,0.f},{0.f,0.f,0.f,0.f}};

    // P3: chunk pipeline — produce(ch+1) overlaps consume(ch)
    mlp_produce(0, h1a, xnl, wfc1t, fc1_b, wid, lr, lk);
    __syncthreads();

    mlp_produce(1, h1b, xnl, wfc1t, fc1_b, wid, lr, lk);
    mlp_consume(0, h1a, wfc2t, acc0, acc1, nb2, lr, lk);
    __syncthreads();

    mlp_produce(2, h1a, xnl, wfc1t, fc1_b, wid, lr, lk);
    mlp_consume(1, h1b, wfc2t, acc0, acc1, nb2, lr, lk);
    __syncthreads();

    mlp_produce(3, h1b, xnl, wfc1t, fc1_b, wid, lr, lk);
    mlp_consume(2, h1a, wfc2t, acc0, acc1, nb2, lr, lk);
    __syncthreads();

    mlp_consume(3, h1b, wfc2t, acc0, acc1, nb2, lr, lk);

    // P4: epilogue — +bias +residual(x3) -> out (f32)
    #pragma unroll
    for (int n = 0; n < 3; ++n) {
        int col = nb2 + n*16 + lr;
        float bias = fc2_b[col];
        #pragma unroll
        for (int r = 0; r < 4; ++r) {
            int row0 = lk*4 + r;
            float v0 = acc0[n][r] + bias + bf2f(x3[row0*X3S + col]);
            float v1 = acc1[n][r] + bias + bf2f(x3[(row0+16)*X3S + col]);
            out[(size_t)(base + row0) * C + col]      = v0;
            out[(size_t)(base + row0 + 16) * C + col] = v1;
        }
    }
}

extern "C" void kernel_launch(void* const* d_in, const int* in_sizes, int n_in,
                              void* d_out, int out_size, void* d_ws, size_t ws_size,
                              hipStream_t stream)
{
    const float* x      = (const float*)d_in[0];
    const float* ln1_w  = (const float*)d_in[1];
    const float* ln1_b  = (const float*)d_in[2];
    const float* qkv_w  = (const float*)d_in[3];
    const float* qkv_b  = (const float*)d_in[4];
    const float* biases = (const float*)d_in[5];
    const float* proj_w = (const float*)d_in[6];
    const float* proj_b = (const float*)d_in[7];
    const float* conv_w = (const float*)d_in[8];
    const float* bn_g   = (const float*)d_in[9];
    const float* bn_b   = (const float*)d_in[10];
    const float* bn_m   = (const float*)d_in[11];
    const float* bn_v   = (const float*)d_in[12];
    const float* ln2_w  = (const float*)d_in[13];
    const float* ln2_b  = (const float*)d_in[14];
    const float* fc1_w  = (const float*)d_in[15];
    const float* fc1_b  = (const float*)d_in[16];
    const float* fc2_w  = (const float*)d_in[17];
    const float* fc2_b  = (const float*)d_in[18];
    const int* bidx     = (const int*)d_in[19];

    char* ws = (char*)d_ws;
    unsigned short* x2    = (unsigned short*)ws;                  // 25,165,824 B
    unsigned short* wfc1t = (unsigned short*)(ws + 25165824);     // 294,912 B
    unsigned short* wfc2t = (unsigned short*)(ws + 25460736);     // 294,912 B
    unsigned short* wqkvt = (unsigned short*)(ws + 25755648);     // 221,184 B
    unsigned short* wprojt= (unsigned short*)(ws + 25976832);     // 73,728 B
    float*          biasfp= (float*)(ws + 26050560);              // 98,304 B
    float*          bnsc  = (float*)(ws + 26148864);              // 768 B
    float*          bnsh  = (float*)(ws + 26149632);              // 768 B
    float* out = (float*)d_out;
    int noff = in_sizes[5] / NHh;

    prep_kernel<<<(467136 + 255)/256, 256, 0, stream>>>(
        fc1_w, fc2_w, qkv_w, proj_w, biases, noff, bidx,
        bn_g, bn_b, bn_m, bn_v,
        wfc1t, wfc2t, wqkvt, wprojt, biasfp, bnsc, bnsh);

    size_t smem1 = 122368;
    hipFuncSetAttribute((const void*)attn_win_mfma,
                        hipFuncAttributeMaxDynamicSharedMemorySize, (int)smem1);
    attn_win_mfma<<<16*100, 512, smem1, stream>>>(
        x, ln1_w, ln1_b, wqkvt, qkv_b, biasfp, wprojt, proj_b, x2);

    size_t smem2 = 51456;
    hipFuncSetAttribute((const void*)conv_mlp2,
                        hipFuncAttributeMaxDynamicSharedMemorySize, (int)smem2);
    conv_mlp2<<<65536/32, 256, smem2, stream>>>(
        x2, conv_w, bnsc, bnsh, ln2_w, ln2_b,
        wfc1t, fc1_b, wfc2t, fc2_b, out);
}

// Round 9
// 453.525 us; speedup vs baseline: 8.5441x; 1.2175x over previous
//
#include <hip/hip_runtime.h>
#include <hip/hip_bf16.h>

#define C 192
#define NHh 6
#define NT 49
#define IMG 64
#define WSZ 7

#define XS2 200   // xn/ao LDS stride (bf16)
#define QKS 392
#define VTS 72
#define PLS 72
#define X3S 200   // conv_mlp3 row stride (bf16)

typedef __attribute__((ext_vector_type(8))) short bf16x8;
typedef __attribute__((ext_vector_type(4))) float f32x4;

__device__ __forceinline__ float bf2f(unsigned short u) {
    union { unsigned int i; float f; } v; v.i = ((unsigned int)u) << 16; return v.f;
}
__device__ __forceinline__ unsigned short f2bf(float f) {
    __hip_bfloat16 h = __float2bfloat16(f);
    return *(unsigned short*)&h;
}
__device__ __forceinline__ float gelu_f(float v) {
    return 0.5f * v * (1.f + erff(v * 0.70710678118654752f));
}

// ---------------- prep A: LDS-tiled transposes (coalesced read AND write) ----------------
// blocks 0..107: 64x64 f32->bf16 transpose tiles; 108..203: biasfp; 204: bn + convwt
__global__ __launch_bounds__(256) void prep_kernel(
    const float* __restrict__ fc1_w, const float* __restrict__ fc2_w,
    const float* __restrict__ qkv_w, const float* __restrict__ proj_w,
    const float* __restrict__ biases, int noff, const int* __restrict__ bidx,
    const float* __restrict__ bn_g, const float* __restrict__ bn_b,
    const float* __restrict__ bn_m, const float* __restrict__ bn_v,
    const float* __restrict__ conv_w,
    unsigned short* __restrict__ wfc1t, unsigned short* __restrict__ wfc2t,
    unsigned short* __restrict__ wqkvt, unsigned short* __restrict__ wprojt,
    float* __restrict__ biasfp, float* __restrict__ bnsc, float* __restrict__ bnsh,
    float* __restrict__ convwt)
{
    __shared__ unsigned short tbuf[64 * 68];
    const int bid = blockIdx.x, tid = threadIdx.x;

    if (bid < 108) {
        const float* src; unsigned short* dst; int K, N, tk, tn;
        if (bid < 36)      { src = fc1_w;  dst = wfc1t;  K = 192; N = 768; tk = bid/12;      tn = bid%12; }
        else if (bid < 72) { src = fc2_w;  dst = wfc2t;  K = 768; N = 192; tk = (bid-36)/3;  tn = (bid-36)%3; }
        else if (bid < 99) { src = qkv_w;  dst = wqkvt;  K = 192; N = 576; tk = (bid-72)/9;  tn = (bid-72)%9; }
        else               { src = proj_w; dst = wprojt; K = 192; N = 192; tk = (bid-99)/3;  tn = (bid-99)%3; }
        // phase 1: coalesced f32 read -> bf16 LDS
        for (int i = tid; i < 1024; i += 256) {
            int r = i >> 4, c = (i & 15) * 4;
            float4 v = *(const float4*)(src + (size_t)(tk*64 + r) * N + tn*64 + c);
            ushort4 s; s.x = f2bf(v.x); s.y = f2bf(v.y); s.z = f2bf(v.z); s.w = f2bf(v.w);
            *(ushort4*)&tbuf[r*68 + c] = s;
        }
        __syncthreads();
        // phase 2: transpose out, coalesced ushort4 writes
        for (int i = tid; i < 1024; i += 256) {
            int n = i >> 4, k = (i & 15) * 4;
            ushort4 o;
            o.x = tbuf[(k+0)*68 + n];
            o.y = tbuf[(k+1)*68 + n];
            o.z = tbuf[(k+2)*68 + n];
            o.w = tbuf[(k+3)*68 + n];
            *(ushort4*)(dst + (size_t)(tn*64 + n) * K + tk*64 + k) = o;
        }
    } else if (bid < 204) {
        int j = (bid - 108) * 256 + tid;
        if (j < 24576) {
            int h = j >> 12, rem = j & 4095;
            int q = rem >> 6, k = rem & 63;
            biasfp[j] = (q < NT && k < NT) ? biases[h * noff + bidx[q * NT + k]] : -1.0e30f;
        }
    } else {
        for (int it = tid; it < 1920; it += 256) {
            if (it < 192) {
                float sc = bn_g[it] * rsqrtf(bn_v[it] + 1e-5f);
                bnsc[it] = sc;
                bnsh[it] = bn_b[it] - bn_m[it] * sc;
            } else {
                int idx = it - 192;
                int tap = idx / 192, c = idx - tap * 192;
                convwt[tap * 192 + c] = conv_w[c * 9 + tap];
            }
        }
    }
}

// ---------------- K1 (MFMA, 8 waves): LN1 -> qkv -> windowed attn -> proj + residual ----------------
__global__ __launch_bounds__(512) void attn_win_mfma(
    const float* __restrict__ x,
    const float* __restrict__ ln1_w, const float* __restrict__ ln1_b,
    const unsigned short* __restrict__ wqkvt, const float* __restrict__ qkv_b,
    const float* __restrict__ biasfp,
    const unsigned short* __restrict__ wprojt, const float* __restrict__ proj_b,
    unsigned short* __restrict__ x2)
{
    extern __shared__ char smem[];
    unsigned short* xn = (unsigned short*)smem;               // [64][XS2]  25600 B (reused as ao)
    unsigned short* qk = (unsigned short*)(smem + 25600);     // [64][QKS]  50176 B
    unsigned short* vt = (unsigned short*)(smem + 75776);     // [6*32][VTS] 27648 B
    unsigned short* pl = (unsigned short*)(smem + 103424);    // [8][16][PLS] 18432 B
    float* stats = (float*)(smem + 121856);                   // [64][2] 512 B

    const int tid = threadIdx.x;
    const int blk = blockIdx.x;
    const int b  = blk / 100;
    const int wi = (blk / 10) % 10;
    const int wj = blk % 10;
    const size_t base = (size_t)b * 4096;
    const int wid = tid >> 6, lane = tid & 63, lr = lane & 15, lg = lane >> 4;

    for (int idx = tid; idx < 64*48; idx += 512) {
        int t = idx / 48, c0 = (idx - t*48) * 4;
        ushort4 sv; sv.x = 0; sv.y = 0; sv.z = 0; sv.w = 0;
        if (t < NT) {
            int gh = wi*WSZ + t/WSZ, gw = wj*WSZ + t%WSZ;
            if (gh < IMG && gw < IMG) {
                float4 v = *(const float4*)(x + (base + (size_t)(gh*IMG + gw))*C + c0);
                sv.x = f2bf(v.x); sv.y = f2bf(v.y); sv.z = f2bf(v.z); sv.w = f2bf(v.w);
            }
        }
        *(ushort4*)&xn[t*XS2 + c0] = sv;
    }
    __syncthreads();

    {
        int lt = tid >> 3, sl = tid & 7;
        float s = 0.f, s2 = 0.f;
        for (int c = sl; c < C; c += 8) {
            float v = bf2f(xn[lt*XS2 + c]);
            s += v; s2 += v*v;
        }
        #pragma unroll
        for (int msk = 1; msk < 8; msk <<= 1) {
            s  += __shfl_xor(s,  msk, 64);
            s2 += __shfl_xor(s2, msk, 64);
        }
        if (sl == 0) {
            float m = s * (1.f/C), var = s2 * (1.f/C) - m*m;
            stats[2*lt]   = m;
            stats[2*lt+1] = rsqrtf(var + 1e-5f);
        }
    }
    __syncthreads();

    for (int idx = tid; idx < 64*48; idx += 512) {
        int t = idx / 48, c0 = (idx - t*48) * 4;
        float mm = stats[2*t], rr = stats[2*t+1];
        ushort4 sv = *(ushort4*)&xn[t*XS2 + c0];
        sv.x = f2bf((bf2f(sv.x) - mm) * rr * ln1_w[c0+0] + ln1_b[c0+0]);
        sv.y = f2bf((bf2f(sv.y) - mm) * rr * ln1_w[c0+1] + ln1_b[c0+1]);
        sv.z = f2bf((bf2f(sv.z) - mm) * rr * ln1_w[c0+2] + ln1_b[c0+2]);
        sv.w = f2bf((bf2f(sv.w) - mm) * rr * ln1_w[c0+3] + ln1_b[c0+3]);
        *(ushort4*)&xn[t*XS2 + c0] = sv;
    }
    __syncthreads();

    for (int nt = wid; nt < 36; nt += 8) {
        const int ncol = nt*16 + lr;
        f32x4 acc0 = {0.f,0.f,0.f,0.f}, acc1 = {0.f,0.f,0.f,0.f};
        f32x4 acc2 = {0.f,0.f,0.f,0.f}, acc3 = {0.f,0.f,0.f,0.f};
        const unsigned short* wp = wqkvt + ncol*192 + lg*8;
        #pragma unroll
        for (int ks = 0; ks < 6; ++ks) {
            bf16x8 bfr = *(const bf16x8*)(wp + ks*32);
            bf16x8 a0 = *(const bf16x8*)(xn + (0*16+lr)*XS2 + ks*32 + lg*8);
            bf16x8 a1 = *(const bf16x8*)(xn + (1*16+lr)*XS2 + ks*32 + lg*8);
            bf16x8 a2 = *(const bf16x8*)(xn + (2*16+lr)*XS2 + ks*32 + lg*8);
            bf16x8 a3 = *(const bf16x8*)(xn + (3*16+lr)*XS2 + ks*32 + lg*8);
            acc0 = __builtin_amdgcn_mfma_f32_16x16x32_bf16(a0, bfr, acc0, 0, 0, 0);
            acc1 = __builtin_amdgcn_mfma_f32_16x16x32_bf16(a1, bfr, acc1, 0, 0, 0);
            acc2 = __builtin_amdgcn_mfma_f32_16x16x32_bf16(a2, bfr, acc2, 0, 0, 0);
            acc3 = __builtin_amdgcn_mfma_f32_16x16x32_bf16(a3, bfr, acc3, 0, 0, 0);
        }
        float bias = qkv_b[ncol];
        const int h = ncol / 96, wo = ncol - h*96;
        #pragma unroll
        for (int mt = 0; mt < 4; ++mt) {
            f32x4 av = (mt==0) ? acc0 : (mt==1) ? acc1 : (mt==2) ? acc2 : acc3;
            #pragma unroll
            for (int r = 0; r < 4; ++r) {
                int tok = mt*16 + lg*4 + r;
                unsigned short v = f2bf(av[r] + bias);
                if (wo < 64) qk[tok*QKS + h*64 + wo] = v;
                else         vt[(h*32 + (wo-64))*VTS + tok] = v;
            }
        }
    }
    __syncthreads();

    unsigned short* ao = xn;
    for (int u = wid; u < 24; u += 8) {
        const int h = u >> 2, nq = u & 3;
        const int qg = nq*16 + lr;
        f32x4 s0 = {0.f,0.f,0.f,0.f}, s1 = {0.f,0.f,0.f,0.f};
        f32x4 s2 = {0.f,0.f,0.f,0.f}, s3 = {0.f,0.f,0.f,0.f};
        bf16x8 qf = *(const bf16x8*)(qk + qg*QKS + h*64 + lg*8);
        bf16x8 k0 = *(const bf16x8*)(qk + (0*16+lr)*QKS + h*64 + 32 + lg*8);
        bf16x8 k1 = *(const bf16x8*)(qk + (1*16+lr)*QKS + h*64 + 32 + lg*8);
        bf16x8 k2 = *(const bf16x8*)(qk + (2*16+lr)*QKS + h*64 + 32 + lg*8);
        bf16x8 k3 = *(const bf16x8*)(qk + (3*16+lr)*QKS + h*64 + 32 + lg*8);
        s0 = __builtin_amdgcn_mfma_f32_16x16x32_bf16(k0, qf, s0, 0, 0, 0);
        s1 = __builtin_amdgcn_mfma_f32_16x16x32_bf16(k1, qf, s1, 0, 0, 0);
        s2 = __builtin_amdgcn_mfma_f32_16x16x32_bf16(k2, qf, s2, 0, 0, 0);
        s3 = __builtin_amdgcn_mfma_f32_16x16x32_bf16(k3, qf, s3, 0, 0, 0);
        const float* bp = biasfp + (size_t)(h*64 + qg)*64 + lg*4;
        float sv[4][4];
        float mx = -3.0e38f;
        #pragma unroll
        for (int mk = 0; mk < 4; ++mk) {
            f32x4 sa = (mk==0) ? s0 : (mk==1) ? s1 : (mk==2) ? s2 : s3;
            float4 b4 = *(const float4*)(bp + mk*16);
            sv[mk][0] = sa[0] * 0.17677669529663687f + b4.x;
            sv[mk][1] = sa[1] * 0.17677669529663687f + b4.y;
            sv[mk][2] = sa[2] * 0.17677669529663687f + b4.z;
            sv[mk][3] = sa[3] * 0.17677669529663687f + b4.w;
            #pragma unroll
            for (int r = 0; r < 4; ++r) mx = fmaxf(mx, sv[mk][r]);
        }
        mx = fmaxf(mx, __shfl_xor(mx, 16, 64));
        mx = fmaxf(mx, __shfl_xor(mx, 32, 64));
        float sum = 0.f;
        #pragma unroll
        for (int mk = 0; mk < 4; ++mk)
            #pragma unroll
            for (int r = 0; r < 4; ++r) { sv[mk][r] = __expf(sv[mk][r] - mx); sum += sv[mk][r]; }
        sum += __shfl_xor(sum, 16, 64);
        sum += __shfl_xor(sum, 32, 64);
        float inv = 1.f / sum;
        unsigned short* pw = pl + (wid*16 + lr)*PLS;
        #pragma unroll
        for (int mk = 0; mk < 4; ++mk)
            #pragma unroll
            for (int r = 0; r < 4; ++r) pw[mk*16 + lg*4 + r] = f2bf(sv[mk][r] * inv);
        #pragma unroll
        for (int dt = 0; dt < 2; ++dt) {
            f32x4 oa = {0.f,0.f,0.f,0.f};
            #pragma unroll
            for (int kk = 0; kk < 2; ++kk) {
                bf16x8 vf = *(const bf16x8*)(vt + (h*32 + dt*16 + lr)*VTS + kk*32 + lg*8);
                bf16x8 pf = *(const bf16x8*)(pl + (wid*16 + lr)*PLS + kk*32 + lg*8);
                oa = __builtin_amdgcn_mfma_f32_16x16x32_bf16(vf, pf, oa, 0, 0, 0);
            }
            #pragma unroll
            for (int r = 0; r < 4; ++r)
                ao[(nq*16 + lr)*XS2 + h*32 + dt*16 + lg*4 + r] = f2bf(oa[r]);
        }
    }
    __syncthreads();

    for (int nt = wid; nt < 12; nt += 8) {
        const int ncol = nt*16 + lr;
        f32x4 acc0 = {0.f,0.f,0.f,0.f}, acc1 = {0.f,0.f,0.f,0.f};
        f32x4 acc2 = {0.f,0.f,0.f,0.f}, acc3 = {0.f,0.f,0.f,0.f};
        const unsigned short* wp = wprojt + ncol*192 + lg*8;
        #pragma unroll
        for (int ks = 0; ks < 6; ++ks) {
            bf16x8 bfr = *(const bf16x8*)(wp + ks*32);
            bf16x8 a0 = *(const bf16x8*)(ao + (0*16+lr)*XS2 + ks*32 + lg*8);
            bf16x8 a1 = *(const bf16x8*)(ao + (1*16+lr)*XS2 + ks*32 + lg*8);
            bf16x8 a2 = *(const bf16x8*)(ao + (2*16+lr)*XS2 + ks*32 + lg*8);
            bf16x8 a3 = *(const bf16x8*)(ao + (3*16+lr)*XS2 + ks*32 + lg*8);
            acc0 = __builtin_amdgcn_mfma_f32_16x16x32_bf16(a0, bfr, acc0, 0, 0, 0);
            acc1 = __builtin_amdgcn_mfma_f32_16x16x32_bf16(a1, bfr, acc1, 0, 0, 0);
            acc2 = __builtin_amdgcn_mfma_f32_16x16x32_bf16(a2, bfr, acc2, 0, 0, 0);
            acc3 = __builtin_amdgcn_mfma_f32_16x16x32_bf16(a3, bfr, acc3, 0, 0, 0);
        }
        float bias = proj_b[ncol];
        #pragma unroll
        for (int mt = 0; mt < 4; ++mt) {
            f32x4 av = (mt==0) ? acc0 : (mt==1) ? acc1 : (mt==2) ? acc2 : acc3;
            #pragma unroll
            for (int r = 0; r < 4; ++r) {
                int tok = mt*16 + lg*4 + r;
                if (tok >= NT) continue;
                int gh = wi*WSZ + tok/WSZ, gw = wj*WSZ + tok%WSZ;
                if (gh >= IMG || gw >= IMG) continue;
                size_t g = (base + (size_t)(gh*IMG + gw))*C + ncol;
                x2[g] = f2bf(av[r] + bias + x[g]);
            }
        }
    }
}

// ---- fc1-chunk produce / fc2-chunk consume helpers (chunk = 192 hidden cols) ----
__device__ __forceinline__ f32x4 mfma16(bf16x8 a, bf16x8 b, f32x4 c) {
    return __builtin_amdgcn_mfma_f32_16x16x32_bf16(a, b, c, 0, 0, 0);
}

__device__ __forceinline__ void mlp_produce(
    int ch, unsigned short* buf, const unsigned short* xnl,
    const unsigned short* __restrict__ wfc1t, const float* __restrict__ fc1_b,
    int wid, int lr, int lk)
{
    bf16x8 xa0[6], xa1[6];
    #pragma unroll
    for (int ks = 0; ks < 6; ++ks) {
        xa0[ks] = *(const bf16x8*)(xnl + lr*X3S + ks*32 + lk*8);
        xa1[ks] = *(const bf16x8*)(xnl + (16+lr)*X3S + ks*32 + lk*8);
    }
    #pragma unroll
    for (int t = 0; t < 3; ++t) {
        const int nl = (wid*3 + t)*16 + lr;
        const int ncol = ch*192 + nl;
        f32x4 a0 = {0.f,0.f,0.f,0.f}, a1 = {0.f,0.f,0.f,0.f};
        const unsigned short* wp = wfc1t + (size_t)ncol*192 + lk*8;
        #pragma unroll
        for (int ks = 0; ks < 6; ++ks) {
            bf16x8 bfr = *(const bf16x8*)(wp + ks*32);
            a0 = mfma16(xa0[ks], bfr, a0);
            a1 = mfma16(xa1[ks], bfr, a1);
        }
        float bias = fc1_b[ncol];
        #pragma unroll
        for (int r = 0; r < 4; ++r) {
            int row0 = lk*4 + r;
            buf[row0*X3S + nl]      = f2bf(gelu_f(a0[r] + bias));
            buf[(row0+16)*X3S + nl] = f2bf(gelu_f(a1[r] + bias));
        }
    }
}

__device__ __forceinline__ void mlp_consume(
    int ch, const unsigned short* buf,
    const unsigned short* __restrict__ wfc2t,
    f32x4* acc0, f32x4* acc1, int nb2, int lr, int lk)
{
    #pragma unroll
    for (int ks = 0; ks < 6; ++ks) {
        bf16x8 af0 = *(const bf16x8*)(buf + lr*X3S + ks*32 + lk*8);
        bf16x8 af1 = *(const bf16x8*)(buf + (16+lr)*X3S + ks*32 + lk*8);
        #pragma unroll
        for (int n = 0; n < 3; ++n) {
            bf16x8 b = *(const bf16x8*)(wfc2t + (size_t)(nb2 + n*16 + lr)*768 + ch*192 + ks*32 + lk*8);
            acc0[n] = mfma16(af0, b, acc0[n]);
            acc1[n] = mfma16(af1, b, acc1[n]);
        }
    }
}

// -------- K2 (fused, MFMA, 4 blocks/CU): conv3x3+BN -> out(global f32) + in-wave LN2 ->
//          xnl LDS ; fc1/fc2 chunk dbuf pipeline ; epilogue + residual(out) -> out --------
__global__ __launch_bounds__(256, 4) void conv_mlp3(
    const unsigned short* __restrict__ x2,
    const float* __restrict__ convwt,
    const float* __restrict__ bnsc, const float* __restrict__ bnsh,
    const float* __restrict__ ln2_w, const float* __restrict__ ln2_b,
    const unsigned short* __restrict__ wfc1t, const float* __restrict__ fc1_b,
    const unsigned short* __restrict__ wfc2t, const float* __restrict__ fc2_b,
    float* out)
{
    extern __shared__ char smem[];
    unsigned short* xnl = (unsigned short*)smem;             // [32][X3S] 12800
    unsigned short* h1a = (unsigned short*)(smem + 12800);   // [32][X3S] 12800
    unsigned short* h1b = (unsigned short*)(smem + 25600);   // [32][X3S] 12800

    const int tid  = threadIdx.x;
    const int base = blockIdx.x * 32;
    const int b    = base >> 12;
    const int n0   = base & 4095;
    const int hh   = n0 >> 6;
    const int w0v  = n0 & 63;
    const size_t ibase = (size_t)b * 4096;

    // P0: conv+BN (8 lanes/token, 6 quads each) -> x3 regs -> global out + in-wave LN2 -> xnl LDS
    {
        const int lt = tid >> 3, sl = tid & 7;   // token lt (0..31), lane-slot sl (0..7)
        const int ww = w0v + lt;
        float4 xv[6];
        #pragma unroll
        for (int j = 0; j < 6; ++j) { xv[j].x = 0.f; xv[j].y = 0.f; xv[j].z = 0.f; xv[j].w = 0.f; }
        #pragma unroll
        for (int kh = -1; kh <= 1; ++kh) {
            int h2 = hh + kh;
            if (h2 < 0 || h2 >= IMG) continue;
            #pragma unroll
            for (int kw = -1; kw <= 1; ++kw) {
                int w2 = ww + kw;
                if (w2 < 0 || w2 >= IMG) continue;
                const unsigned short* src = x2 + (ibase + (size_t)(h2*IMG + w2))*C;
                const float* wt = convwt + ((kh+1)*3 + (kw+1)) * 192;
                #pragma unroll
                for (int j = 0; j < 6; ++j) {
                    int c0 = (sl + 8*j) * 4;
                    ushort4 v = *(const ushort4*)(src + c0);
                    float4 w = *(const float4*)(wt + c0);
                    xv[j].x += bf2f(v.x) * w.x;
                    xv[j].y += bf2f(v.y) * w.y;
                    xv[j].z += bf2f(v.z) * w.z;
                    xv[j].w += bf2f(v.w) * w.w;
                }
            }
        }
        float s = 0.f, s2 = 0.f;
        #pragma unroll
        for (int j = 0; j < 6; ++j) {
            int c0 = (sl + 8*j) * 4;
            float4 sc = *(const float4*)(bnsc + c0);
            float4 sh = *(const float4*)(bnsh + c0);
            xv[j].x = xv[j].x * sc.x + sh.x;
            xv[j].y = xv[j].y * sc.y + sh.y;
            xv[j].z = xv[j].z * sc.z + sh.z;
            xv[j].w = xv[j].w * sc.w + sh.w;
            *(float4*)(out + ((size_t)base + lt)*C + c0) = xv[j];   // x3 -> residual store
            s  += xv[j].x + xv[j].y + xv[j].z + xv[j].w;
            s2 += xv[j].x*xv[j].x + xv[j].y*xv[j].y + xv[j].z*xv[j].z + xv[j].w*xv[j].w;
        }
        #pragma unroll
        for (int msk = 1; msk < 8; msk <<= 1) {
            s  += __shfl_xor(s,  msk, 64);
            s2 += __shfl_xor(s2, msk, 64);
        }
        float m = s * (1.f/C), var = s2 * (1.f/C) - m*m;
        float rs = rsqrtf(var + 1e-5f);
        #pragma unroll
        for (int j = 0; j < 6; ++j) {
            int c0 = (sl + 8*j) * 4;
            float4 lw = *(const float4*)(ln2_w + c0);
            float4 lb = *(const float4*)(ln2_b + c0);
            ushort4 sv;
            sv.x = f2bf((xv[j].x - m) * rs * lw.x + lb.x);
            sv.y = f2bf((xv[j].y - m) * rs * lw.y + lb.y);
            sv.z = f2bf((xv[j].z - m) * rs * lw.z + lb.z);
            sv.w = f2bf((xv[j].w - m) * rs * lw.w + lb.w);
            *(ushort4*)&xnl[lt*X3S + c0] = sv;
        }
    }
    __syncthreads();

    const int wid = tid >> 6, l = tid & 63, lr = l & 15, lk = l >> 4;
    const int nb2 = wid * 48;

    f32x4 acc0[3] = {{0.f,0.f,0.f,0.f},{0.f,0.f,0.f,0.f},{0.f,0.f,0.f,0.f}};
    f32x4 acc1[3] = {{0.f,0.f,0.f,0.f},{0.f,0.f,0.f,0.f},{0.f,0.f,0.f,0.f}};

    mlp_produce(0, h1a, xnl, wfc1t, fc1_b, wid, lr, lk);
    __syncthreads();
    mlp_produce(1, h1b, xnl, wfc1t, fc1_b, wid, lr, lk);
    mlp_consume(0, h1a, wfc2t, acc0, acc1, nb2, lr, lk);
    __syncthreads();
    mlp_produce(2, h1a, xnl, wfc1t, fc1_b, wid, lr, lk);
    mlp_consume(1, h1b, wfc2t, acc0, acc1, nb2, lr, lk);
    __syncthreads();
    mlp_produce(3, h1b, xnl, wfc1t, fc1_b, wid, lr, lk);
    mlp_consume(2, h1a, wfc2t, acc0, acc1, nb2, lr, lk);
    __syncthreads();
    mlp_consume(3, h1b, wfc2t, acc0, acc1, nb2, lr, lk);

    // epilogue: +bias +residual (x3 re-read from global, L2/L3-hot) -> out
    #pragma unroll
    for (int n = 0; n < 3; ++n) {
        int col = nb2 + n*16 + lr;
        float bias = fc2_b[col];
        #pragma unroll
        for (int r = 0; r < 4; ++r) {
            int row0 = lk*4 + r;
            size_t g0 = (size_t)(base + row0) * C + col;
            size_t g1 = (size_t)(base + row0 + 16) * C + col;
            float v0 = acc0[n][r] + bias + out[g0];
            float v1 = acc1[n][r] + bias + out[g1];
            out[g0] = v0;
            out[g1] = v1;
        }
    }
}

extern "C" void kernel_launch(void* const* d_in, const int* in_sizes, int n_in,
                              void* d_out, int out_size, void* d_ws, size_t ws_size,
                              hipStream_t stream)
{
    const float* x      = (const float*)d_in[0];
    const float* ln1_w  = (const float*)d_in[1];
    const float* ln1_b  = (const float*)d_in[2];
    const float* qkv_w  = (const float*)d_in[3];
    const float* qkv_b  = (const float*)d_in[4];
    const float* biases = (const float*)d_in[5];
    const float* proj_w = (const float*)d_in[6];
    const float* proj_b = (const float*)d_in[7];
    const float* conv_w = (const float*)d_in[8];
    const float* bn_g   = (const float*)d_in[9];
    const float* bn_b   = (const float*)d_in[10];
    const float* bn_m   = (const float*)d_in[11];
    const float* bn_v   = (const float*)d_in[12];
    const float* ln2_w  = (const float*)d_in[13];
    const float* ln2_b  = (const float*)d_in[14];
    const float* fc1_w  = (const float*)d_in[15];
    const float* fc1_b  = (const float*)d_in[16];
    const float* fc2_w  = (const float*)d_in[17];
    const float* fc2_b  = (const float*)d_in[18];
    const int* bidx     = (const int*)d_in[19];

    char* ws = (char*)d_ws;
    unsigned short* x2    = (unsigned short*)ws;                  // 25,165,824 B
    unsigned short* wfc1t = (unsigned short*)(ws + 25165824);     // 294,912 B
    unsigned short* wfc2t = (unsigned short*)(ws + 25460736);     // 294,912 B
    unsigned short* wqkvt = (unsigned short*)(ws + 25755648);     // 221,184 B
    unsigned short* wprojt= (unsigned short*)(ws + 25976832);     // 73,728 B
    float*          biasfp= (float*)(ws + 26050560);              // 98,304 B
    float*          bnsc  = (float*)(ws + 26148864);              // 768 B
    float*          bnsh  = (float*)(ws + 26149632);              // 768 B
    float*          convwt= (float*)(ws + 26150400);              // 6,912 B
    float* out = (float*)d_out;
    int noff = in_sizes[5] / NHh;

    prep_kernel<<<205, 256, 0, stream>>>(
        fc1_w, fc2_w, qkv_w, proj_w, biases, noff, bidx,
        bn_g, bn_b, bn_m, bn_v, conv_w,
        wfc1t, wfc2t, wqkvt, wprojt, biasfp, bnsc, bnsh, convwt);

    size_t smem1 = 122368;
    hipFuncSetAttribute((const void*)attn_win_mfma,
                        hipFuncAttributeMaxDynamicSharedMemorySize, (int)smem1);
    attn_win_mfma<<<16*100, 512, smem1, stream>>>(
        x, ln1_w, ln1_b, wqkvt, qkv_b, biasfp, wprojt, proj_b, x2);

    size_t smem2 = 38400;
    hipFuncSetAttribute((const void*)conv_mlp3,
                        hipFuncAttributeMaxDynamicSharedMemorySize, (int)smem2);
    conv_mlp3<<<65536/32, 256, smem2, stream>>>(
        x2, convwt, bnsc, bnsh, ln2_w, ln2_b,
        wfc1t, fc1_b, wfc2t, fc2_b, out);
}